// Round 1
// baseline (2315.441 us; speedup 1.0000x reference)
//
#include <hip/hip_runtime.h>
#include <math.h>

constexpr int N = 200000;
constexpr int E = 800000;
constexpr int G = 8192;
constexpr int H = 128;

// ---------------- utility kernels ----------------

__global__ void zero2_kernel(int* __restrict__ a, int na, int* __restrict__ b, int nb) {
  int i = blockIdx.x * blockDim.x + threadIdx.x;
  int stride = gridDim.x * blockDim.x;
  int total = na + nb;
  for (; i < total; i += stride) {
    if (i < na) a[i] = 0; else b[i - na] = 0;
  }
}

__global__ void hist_kernel(const int* __restrict__ idx, int* __restrict__ cnt, int n) {
  int i = blockIdx.x * blockDim.x + threadIdx.x;
  int stride = gridDim.x * blockDim.x;
  for (; i < n; i += stride) atomicAdd(&cnt[idx[i]], 1);
}

// single-block exclusive scan, out has n+1 entries (out[n] = total)
__global__ void scan_excl_kernel(const int* __restrict__ in, int* __restrict__ out, int n) {
  __shared__ int part[1024];
  int t = threadIdx.x;
  int chunk = (n + 1023) >> 10;
  int lo = t * chunk;
  int hi = min(lo + chunk, n);
  int s = 0;
  for (int i = lo; i < hi; ++i) s += in[i];
  part[t] = s;
  __syncthreads();
  for (int off = 1; off < 1024; off <<= 1) {
    int v = 0;
    if (t >= off) v = part[t - off];
    __syncthreads();
    part[t] += v;
    __syncthreads();
  }
  int run = (t > 0) ? part[t - 1] : 0;
  for (int i = lo; i < hi; ++i) { out[i] = run; run += in[i]; }
  if (t == 1023) out[n] = run;
}

__global__ void prep_kernel(const int* __restrict__ deg, const int* __restrict__ rowstart,
                            float* __restrict__ dinv, int* __restrict__ cursor, int n) {
  int i = blockIdx.x * blockDim.x + threadIdx.x;
  int stride = gridDim.x * blockDim.x;
  for (; i < n; i += stride) {
    dinv[i] = 1.0f / sqrtf((float)deg[i] + 1.0f);
    cursor[i] = rowstart[i];
  }
}

__global__ void csr_fill_kernel(const int* __restrict__ src, const int* __restrict__ dst,
                                int* __restrict__ cursor, int* __restrict__ csr, int e) {
  int i = blockIdx.x * blockDim.x + threadIdx.x;
  int stride = gridDim.x * blockDim.x;
  for (; i < e; i += stride) {
    int d = dst[i];
    int p = atomicAdd(&cursor[d], 1);
    csr[p] = src[i];
  }
}

// h[n][j] = relu(x[n]*W_in[j] + b_in[j]); 32 lanes per node, float4 cols
__global__ void in_layer_kernel(const float* __restrict__ x, const float* __restrict__ Win,
                                const float* __restrict__ bin, float* __restrict__ h, int n) {
  int idx = blockIdx.x * blockDim.x + threadIdx.x;
  int node = idx >> 5;
  int lane = idx & 31;
  if (node >= n) return;
  float xv = x[node];
  float4 w = ((const float4*)Win)[lane];
  float4 b = ((const float4*)bin)[lane];
  float4 r;
  r.x = fmaxf(fmaf(xv, w.x, b.x), 0.f);
  r.y = fmaxf(fmaf(xv, w.y, b.y), 0.f);
  r.z = fmaxf(fmaf(xv, w.z, b.z), 0.f);
  r.w = fmaxf(fmaf(xv, w.w, b.w), 0.f);
  ((float4*)h)[node * 32 + lane] = r;
}

// ---------------- GEMM: C[rows,128] = A[rows,128] @ W[128,128] (+bias, relu) ----------------
template <bool EPI>
__global__ __launch_bounds__(256) void gemm128_kernel(const float* __restrict__ A,
                                                      const float* __restrict__ W,
                                                      const float* __restrict__ bias,
                                                      float* __restrict__ C, int rows) {
  __shared__ float sW[H * H];     // 64 KiB
  __shared__ float sA[32 * H];    // 16 KiB
  int t = threadIdx.x;
  for (int i = t; i < H * H / 4; i += 256)
    ((float4*)sW)[i] = ((const float4*)W)[i];
  int tr = t >> 5;   // 0..7 row-group
  int tc = t & 31;   // 0..31 col-group (4 cols each)
  float4 bv = {0.f, 0.f, 0.f, 0.f};
  if (EPI) bv = ((const float4*)bias)[tc];
  int ntiles = (rows + 31) >> 5;
  for (int tile = blockIdx.x; tile < ntiles; tile += gridDim.x) {
    int row0 = tile << 5;
    __syncthreads();
    for (int i = t; i < 1024; i += 256) {
      int r = i >> 5, c = i & 31;
      int gr = row0 + r;
      float4 v = {0.f, 0.f, 0.f, 0.f};
      if (gr < rows) v = ((const float4*)A)[(size_t)gr * 32 + c];
      ((float4*)sA)[i] = v;
    }
    __syncthreads();
    float acc[4][4];
#pragma unroll
    for (int i = 0; i < 4; ++i)
#pragma unroll
      for (int j = 0; j < 4; ++j) acc[i][j] = 0.f;
    const float4* sA4 = (const float4*)sA;
    const float4* sW4 = (const float4*)sW;
#pragma unroll 4
    for (int k4 = 0; k4 < 32; ++k4) {
      float4 a0 = sA4[(tr * 4 + 0) * 32 + k4];
      float4 a1 = sA4[(tr * 4 + 1) * 32 + k4];
      float4 a2 = sA4[(tr * 4 + 2) * 32 + k4];
      float4 a3 = sA4[(tr * 4 + 3) * 32 + k4];
      float av[4][4] = {{a0.x, a0.y, a0.z, a0.w},
                        {a1.x, a1.y, a1.z, a1.w},
                        {a2.x, a2.y, a2.z, a2.w},
                        {a3.x, a3.y, a3.z, a3.w}};
#pragma unroll
      for (int kk = 0; kk < 4; ++kk) {
        float4 w = sW4[(k4 * 4 + kk) * 32 + tc];
#pragma unroll
        for (int i = 0; i < 4; ++i) {
          acc[i][0] = fmaf(av[i][kk], w.x, acc[i][0]);
          acc[i][1] = fmaf(av[i][kk], w.y, acc[i][1]);
          acc[i][2] = fmaf(av[i][kk], w.z, acc[i][2]);
          acc[i][3] = fmaf(av[i][kk], w.w, acc[i][3]);
        }
      }
    }
#pragma unroll
    for (int i = 0; i < 4; ++i) {
      int gr = row0 + tr * 4 + i;
      if (gr < rows) {
        float4 r;
        r.x = acc[i][0]; r.y = acc[i][1]; r.z = acc[i][2]; r.w = acc[i][3];
        if (EPI) {
          r.x = fmaxf(r.x + bv.x, 0.f);
          r.y = fmaxf(r.y + bv.y, 0.f);
          r.z = fmaxf(r.z + bv.z, 0.f);
          r.w = fmaxf(r.w + bv.w, 0.f);
        }
        ((float4*)C)[(size_t)gr * 32 + tc] = r;
      }
    }
  }
}

// out[n] = relu( dinv[n]*(sum_in dinv[s]*xw[s] + dinv[n]*xw[n]) + b ); 32 lanes/node
__global__ __launch_bounds__(256) void aggregate_kernel(const float* __restrict__ xw,
                                                        const float* __restrict__ dinv,
                                                        const int* __restrict__ rowstart,
                                                        const int* __restrict__ csr,
                                                        const float* __restrict__ bias,
                                                        float* __restrict__ out, int n) {
  int idx = blockIdx.x * blockDim.x + threadIdx.x;
  int node = idx >> 5;
  int lane = idx & 31;
  if (node >= n) return;
  const float4* xw4 = (const float4*)xw;
  float dn = dinv[node];
  float4 v = xw4[(size_t)node * 32 + lane];
  float4 acc;
  acc.x = dn * v.x; acc.y = dn * v.y; acc.z = dn * v.z; acc.w = dn * v.w;
  int p0 = rowstart[node], p1 = rowstart[node + 1];
  for (int p = p0; p < p1; ++p) {
    int s = csr[p];
    float ds = dinv[s];
    float4 u = xw4[(size_t)s * 32 + lane];
    acc.x = fmaf(ds, u.x, acc.x);
    acc.y = fmaf(ds, u.y, acc.y);
    acc.z = fmaf(ds, u.z, acc.z);
    acc.w = fmaf(ds, u.w, acc.w);
  }
  float4 b = ((const float4*)bias)[lane];
  float4 r;
  r.x = fmaxf(fmaf(dn, acc.x, b.x), 0.f);
  r.y = fmaxf(fmaf(dn, acc.y, b.y), 0.f);
  r.z = fmaxf(fmaf(dn, acc.z, b.z), 0.f);
  r.w = fmaxf(fmaf(dn, acc.w, b.w), 0.f);
  ((float4*)out)[(size_t)node * 32 + lane] = r;
}

// segment-mean pooling: 32 lanes per graph
__global__ void pool_kernel(const float* __restrict__ h, const int* __restrict__ gstart,
                            float* __restrict__ pooled, int g) {
  int idx = blockIdx.x * blockDim.x + threadIdx.x;
  int grp = idx >> 5;
  int lane = idx & 31;
  if (grp >= g) return;
  int n0 = gstart[grp], n1 = gstart[grp + 1];
  const float4* h4 = (const float4*)h;
  float4 acc = {0.f, 0.f, 0.f, 0.f};
  for (int nn = n0; nn < n1; ++nn) {
    float4 v = h4[(size_t)nn * 32 + lane];
    acc.x += v.x; acc.y += v.y; acc.z += v.z; acc.w += v.w;
  }
  float inv = 1.0f / fmaxf((float)(n1 - n0), 1.0f);
  acc.x *= inv; acc.y *= inv; acc.z *= inv; acc.w *= inv;
  ((float4*)pooled)[(size_t)grp * 32 + lane] = acc;
}

// per-graph MLP head: feats[512] -> relu(@W_m1+b_m1)[128] -> @W_m2+b_m2 -> logit
__global__ __launch_bounds__(128) void classifier_kernel(const float* __restrict__ za,
                                                         const float* __restrict__ zb,
                                                         const float* __restrict__ Wm1,
                                                         const float* __restrict__ bm1,
                                                         const float* __restrict__ Wm2,
                                                         const float* __restrict__ bm2,
                                                         float* __restrict__ out, int g) {
  __shared__ float feats[4 * H];
  __shared__ float red[H];
  int gi = blockIdx.x;
  int j = threadIdx.x;
  float a = za[(size_t)gi * H + j];
  float b = zb[(size_t)gi * H + j];
  feats[j] = a;
  feats[H + j] = b;
  feats[2 * H + j] = fabsf(a - b);
  feats[3 * H + j] = a * b;
  __syncthreads();
  float s = bm1[j];
#pragma unroll 8
  for (int k = 0; k < 4 * H; ++k) s = fmaf(feats[k], Wm1[(size_t)k * H + j], s);
  float hid = fmaxf(s, 0.f);
  red[j] = hid * Wm2[j];
  __syncthreads();
  for (int off = 64; off > 0; off >>= 1) {
    if (j < off) red[j] += red[j + off];
    __syncthreads();
  }
  if (j == 0) out[gi] = red[0] + bm2[0];
}

// ---------------- launch ----------------

extern "C" void kernel_launch(void* const* d_in, const int* in_sizes, int n_in,
                              void* d_out, int out_size, void* d_ws, size_t ws_size,
                              hipStream_t stream) {
  const float* xa = (const float*)d_in[0];
  const int* ei_a = (const int*)d_in[1];
  const int* bv_a = (const int*)d_in[2];
  const float* xb = (const float*)d_in[3];
  const int* ei_b = (const int*)d_in[4];
  const int* bv_b = (const int*)d_in[5];
  const float* W_in = (const float*)d_in[6];
  const float* b_in = (const float*)d_in[7];
  const float* W_c[3] = {(const float*)d_in[8], (const float*)d_in[10], (const float*)d_in[12]};
  const float* b_c[3] = {(const float*)d_in[9], (const float*)d_in[11], (const float*)d_in[13]};
  const float* W_out = (const float*)d_in[14];
  const float* b_out = (const float*)d_in[15];
  const float* W_m1 = (const float*)d_in[16];
  const float* b_m1 = (const float*)d_in[17];
  const float* W_m2 = (const float*)d_in[18];
  const float* b_m2 = (const float*)d_in[19];
  float* out = (float*)d_out;

  char* ws = (char*)d_ws;
  size_t off = 0;
  auto alloc = [&](size_t bytes) -> void* {
    void* p = ws + off;
    off += (bytes + 255) & ~(size_t)255;
    return p;
  };
  float* hA = (float*)alloc((size_t)N * H * 4);
  float* hB = (float*)alloc((size_t)N * H * 4);
  int* deg = (int*)alloc((size_t)N * 4);
  int* rowstart = (int*)alloc((size_t)(N + 1) * 4);
  int* cursor = (int*)alloc((size_t)N * 4);
  int* csr = (int*)alloc((size_t)E * 4);
  float* dinv = (float*)alloc((size_t)N * 4);
  int* gcount = (int*)alloc((size_t)G * 4);
  int* gstart = (int*)alloc((size_t)(G + 1) * 4);
  float* za = (float*)alloc((size_t)G * H * 4);
  float* zb = (float*)alloc((size_t)G * H * 4);

  for (int side = 0; side < 2; ++side) {
    const float* x = side ? xb : xa;
    const int* src = side ? ei_b : ei_a;
    const int* dst = src + E;
    const int* bv = side ? bv_b : bv_a;
    float* z = side ? zb : za;

    zero2_kernel<<<816, 256, 0, stream>>>(deg, N, gcount, G);
    hist_kernel<<<3125, 256, 0, stream>>>(dst, deg, E);
    hist_kernel<<<782, 256, 0, stream>>>(bv, gcount, N);
    scan_excl_kernel<<<1, 1024, 0, stream>>>(deg, rowstart, N);
    scan_excl_kernel<<<1, 1024, 0, stream>>>(gcount, gstart, G);
    prep_kernel<<<782, 256, 0, stream>>>(deg, rowstart, dinv, cursor, N);
    csr_fill_kernel<<<3125, 256, 0, stream>>>(src, dst, cursor, csr, E);
    in_layer_kernel<<<(N * 32 + 255) / 256, 256, 0, stream>>>(x, W_in, b_in, hA, N);
    for (int c = 0; c < 3; ++c) {
      gemm128_kernel<false><<<2048, 256, 0, stream>>>(hA, W_c[c], nullptr, hB, N);
      aggregate_kernel<<<(N * 32 + 255) / 256, 256, 0, stream>>>(hB, dinv, rowstart, csr, b_c[c], hA, N);
    }
    pool_kernel<<<(G * 32) / 256, 256, 0, stream>>>(hA, gstart, hB, G);
    gemm128_kernel<true><<<256, 256, 0, stream>>>(hB, W_out, b_out, z, G);
  }
  classifier_kernel<<<G, 128, 0, stream>>>(za, zb, W_m1, b_m1, W_m2, b_m2, out, G);
}

// Round 2
// 1643.292 us; speedup vs baseline: 1.4090x; 1.4090x over previous
//
#include <hip/hip_runtime.h>
#include <math.h>

constexpr int N = 200000;
constexpr int E = 800000;
constexpr int G = 8192;
constexpr int H = 128;
constexpr int NB = (N + 255) / 256;  // 782 blocks for scan

// ---------------- graph-build kernels ----------------

__global__ void hist_kernel(const int* __restrict__ idx, int* __restrict__ cnt, int n) {
  int i = blockIdx.x * blockDim.x + threadIdx.x;
  int stride = gridDim.x * blockDim.x;
  for (; i < n; i += stride) atomicAdd(&cnt[idx[i]], 1);
}

// per-block partial sums of in[] (256 elems/block)
__global__ void blocksum_kernel(const int* __restrict__ in, int* __restrict__ bsum, int n) {
  int i = blockIdx.x * 256 + threadIdx.x;
  int v = (i < n) ? in[i] : 0;
  for (int off = 32; off > 0; off >>= 1) v += __shfl_down(v, off);
  __shared__ int ws[4];
  int lane = threadIdx.x & 63, wv = threadIdx.x >> 6;
  if (lane == 0) ws[wv] = v;
  __syncthreads();
  if (threadIdx.x == 0) bsum[blockIdx.x] = ws[0] + ws[1] + ws[2] + ws[3];
}

// single-block exclusive scan of data[0..n) in place (n <= 1024); *total_out = sum
__global__ void scan_small_kernel(int* __restrict__ data, int n, int* __restrict__ total_out) {
  __shared__ int buf[1024];
  int t = threadIdx.x;
  int v = (t < n) ? data[t] : 0;
  buf[t] = v;
  __syncthreads();
  for (int off = 1; off < 1024; off <<= 1) {
    int y = (t >= off) ? buf[t - off] : 0;
    __syncthreads();
    buf[t] += y;
    __syncthreads();
  }
  if (t < n) data[t] = buf[t] - v;
  if (t == n - 1) *total_out = buf[t];
}

// out[i] = exclusive_scan(in)[i] using scanned block offsets
__global__ void scan_apply_kernel(const int* __restrict__ in, const int* __restrict__ bsum,
                                  int* __restrict__ out, int n) {
  int i = blockIdx.x * 256 + threadIdx.x;
  int v = (i < n) ? in[i] : 0;
  int lane = threadIdx.x & 63, wv = threadIdx.x >> 6;
  int x = v;
  for (int off = 1; off < 64; off <<= 1) {
    int y = __shfl_up(x, off);
    if (lane >= off) x += y;
  }
  __shared__ int ws[4];
  if (lane == 63) ws[wv] = x;
  __syncthreads();
  int woff = 0;
  for (int w = 0; w < wv; ++w) woff += ws[w];
  if (i < n) out[i] = x - v + woff + bsum[blockIdx.x];
}

// batch_vec is sorted: gstart[q] = first index i with bv[i] >= q, gstart[G] = n
__global__ void segstart_kernel(const int* __restrict__ bv, int* __restrict__ gstart, int n, int g) {
  int i = blockIdx.x * blockDim.x + threadIdx.x;
  int stride = gridDim.x * blockDim.x;
  for (; i <= n; i += stride) {
    int cur = (i < n) ? bv[i] : g;
    int prev = (i > 0) ? bv[i - 1] : -1;
    for (int q = prev + 1; q <= cur && q <= g; ++q) gstart[q] = i;
  }
}

__global__ void prep_kernel(const int* __restrict__ deg, const int* __restrict__ rowstart,
                            float* __restrict__ dinv, int* __restrict__ cursor, int n) {
  int i = blockIdx.x * blockDim.x + threadIdx.x;
  int stride = gridDim.x * blockDim.x;
  for (; i < n; i += stride) {
    dinv[i] = 1.0f / sqrtf((float)deg[i] + 1.0f);
    cursor[i] = rowstart[i];
  }
}

__global__ void csr_fill_kernel(const int* __restrict__ src, const int* __restrict__ dst,
                                int* __restrict__ cursor, int* __restrict__ csr, int e) {
  int i = blockIdx.x * blockDim.x + threadIdx.x;
  int stride = gridDim.x * blockDim.x;
  for (; i < e; i += stride) {
    int d = dst[i];
    int p = atomicAdd(&cursor[d], 1);
    csr[p] = src[i];
  }
}

// h[n][j] = relu(x[n]*W_in[j] + b_in[j]); 32 lanes per node, float4 cols
__global__ void in_layer_kernel(const float* __restrict__ x, const float* __restrict__ Win,
                                const float* __restrict__ bin, float* __restrict__ h, int n) {
  int idx = blockIdx.x * blockDim.x + threadIdx.x;
  int node = idx >> 5;
  int lane = idx & 31;
  if (node >= n) return;
  float xv = x[node];
  float4 w = ((const float4*)Win)[lane];
  float4 b = ((const float4*)bin)[lane];
  float4 r;
  r.x = fmaxf(fmaf(xv, w.x, b.x), 0.f);
  r.y = fmaxf(fmaf(xv, w.y, b.y), 0.f);
  r.z = fmaxf(fmaf(xv, w.z, b.z), 0.f);
  r.w = fmaxf(fmaf(xv, w.w, b.w), 0.f);
  ((float4*)h)[node * 32 + lane] = r;
}

// ---------------- GEMM: C[rows,128] = A[rows,128] @ W[128,128] (+bias, relu) ----------------
template <bool EPI>
__global__ __launch_bounds__(256) void gemm128_kernel(const float* __restrict__ A,
                                                      const float* __restrict__ W,
                                                      const float* __restrict__ bias,
                                                      float* __restrict__ C, int rows) {
  __shared__ float sW[H * H];     // 64 KiB
  __shared__ float sA[32 * H];    // 16 KiB
  int t = threadIdx.x;
  for (int i = t; i < H * H / 4; i += 256)
    ((float4*)sW)[i] = ((const float4*)W)[i];
  int tr = t >> 5;   // 0..7 row-group
  int tc = t & 31;   // 0..31 col-group (4 cols each)
  float4 bv = {0.f, 0.f, 0.f, 0.f};
  if (EPI) bv = ((const float4*)bias)[tc];
  int ntiles = (rows + 31) >> 5;
  for (int tile = blockIdx.x; tile < ntiles; tile += gridDim.x) {
    int row0 = tile << 5;
    __syncthreads();
    for (int i = t; i < 1024; i += 256) {
      int r = i >> 5, c = i & 31;
      int gr = row0 + r;
      float4 v = {0.f, 0.f, 0.f, 0.f};
      if (gr < rows) v = ((const float4*)A)[(size_t)gr * 32 + c];
      ((float4*)sA)[i] = v;
    }
    __syncthreads();
    float acc[4][4];
#pragma unroll
    for (int i = 0; i < 4; ++i)
#pragma unroll
      for (int j = 0; j < 4; ++j) acc[i][j] = 0.f;
    const float4* sA4 = (const float4*)sA;
    const float4* sW4 = (const float4*)sW;
#pragma unroll 4
    for (int k4 = 0; k4 < 32; ++k4) {
      float4 a0 = sA4[(tr * 4 + 0) * 32 + k4];
      float4 a1 = sA4[(tr * 4 + 1) * 32 + k4];
      float4 a2 = sA4[(tr * 4 + 2) * 32 + k4];
      float4 a3 = sA4[(tr * 4 + 3) * 32 + k4];
      float av[4][4] = {{a0.x, a0.y, a0.z, a0.w},
                        {a1.x, a1.y, a1.z, a1.w},
                        {a2.x, a2.y, a2.z, a2.w},
                        {a3.x, a3.y, a3.z, a3.w}};
#pragma unroll
      for (int kk = 0; kk < 4; ++kk) {
        float4 w = sW4[(k4 * 4 + kk) * 32 + tc];
#pragma unroll
        for (int i = 0; i < 4; ++i) {
          acc[i][0] = fmaf(av[i][kk], w.x, acc[i][0]);
          acc[i][1] = fmaf(av[i][kk], w.y, acc[i][1]);
          acc[i][2] = fmaf(av[i][kk], w.z, acc[i][2]);
          acc[i][3] = fmaf(av[i][kk], w.w, acc[i][3]);
        }
      }
    }
#pragma unroll
    for (int i = 0; i < 4; ++i) {
      int gr = row0 + tr * 4 + i;
      if (gr < rows) {
        float4 r;
        r.x = acc[i][0]; r.y = acc[i][1]; r.z = acc[i][2]; r.w = acc[i][3];
        if (EPI) {
          r.x = fmaxf(r.x + bv.x, 0.f);
          r.y = fmaxf(r.y + bv.y, 0.f);
          r.z = fmaxf(r.z + bv.z, 0.f);
          r.w = fmaxf(r.w + bv.w, 0.f);
        }
        ((float4*)C)[(size_t)gr * 32 + tc] = r;
      }
    }
  }
}

// out[n] = relu( dinv[n]*(sum_in dinv[s]*xw[s] + dinv[n]*xw[n]) + b ); 32 lanes/node
__global__ __launch_bounds__(256) void aggregate_kernel(const float* __restrict__ xw,
                                                        const float* __restrict__ dinv,
                                                        const int* __restrict__ rowstart,
                                                        const int* __restrict__ csr,
                                                        const float* __restrict__ bias,
                                                        float* __restrict__ out, int n) {
  int idx = blockIdx.x * blockDim.x + threadIdx.x;
  int node = idx >> 5;
  int lane = idx & 31;
  if (node >= n) return;
  const float4* xw4 = (const float4*)xw;
  float dn = dinv[node];
  float4 v = xw4[(size_t)node * 32 + lane];
  float4 acc;
  acc.x = dn * v.x; acc.y = dn * v.y; acc.z = dn * v.z; acc.w = dn * v.w;
  int p0 = rowstart[node], p1 = rowstart[node + 1];
  for (int p = p0; p < p1; ++p) {
    int s = csr[p];
    float ds = dinv[s];
    float4 u = xw4[(size_t)s * 32 + lane];
    acc.x = fmaf(ds, u.x, acc.x);
    acc.y = fmaf(ds, u.y, acc.y);
    acc.z = fmaf(ds, u.z, acc.z);
    acc.w = fmaf(ds, u.w, acc.w);
  }
  float4 b = ((const float4*)bias)[lane];
  float4 r;
  r.x = fmaxf(fmaf(dn, acc.x, b.x), 0.f);
  r.y = fmaxf(fmaf(dn, acc.y, b.y), 0.f);
  r.z = fmaxf(fmaf(dn, acc.z, b.z), 0.f);
  r.w = fmaxf(fmaf(dn, acc.w, b.w), 0.f);
  ((float4*)out)[(size_t)node * 32 + lane] = r;
}

// segment-mean pooling: 32 lanes per graph; counts derived from gstart
__global__ void pool_kernel(const float* __restrict__ h, const int* __restrict__ gstart,
                            float* __restrict__ pooled, int g) {
  int idx = blockIdx.x * blockDim.x + threadIdx.x;
  int grp = idx >> 5;
  int lane = idx & 31;
  if (grp >= g) return;
  int n0 = gstart[grp], n1 = gstart[grp + 1];
  const float4* h4 = (const float4*)h;
  float4 acc = {0.f, 0.f, 0.f, 0.f};
  for (int nn = n0; nn < n1; ++nn) {
    float4 v = h4[(size_t)nn * 32 + lane];
    acc.x += v.x; acc.y += v.y; acc.z += v.z; acc.w += v.w;
  }
  float inv = 1.0f / fmaxf((float)(n1 - n0), 1.0f);
  acc.x *= inv; acc.y *= inv; acc.z *= inv; acc.w *= inv;
  ((float4*)pooled)[(size_t)grp * 32 + lane] = acc;
}

// per-graph MLP head: feats[512] -> relu(@W_m1+b_m1)[128] -> @W_m2+b_m2 -> logit
__global__ __launch_bounds__(128) void classifier_kernel(const float* __restrict__ za,
                                                         const float* __restrict__ zb,
                                                         const float* __restrict__ Wm1,
                                                         const float* __restrict__ bm1,
                                                         const float* __restrict__ Wm2,
                                                         const float* __restrict__ bm2,
                                                         float* __restrict__ out, int g) {
  __shared__ float feats[4 * H];
  __shared__ float red[H];
  int gi = blockIdx.x;
  int j = threadIdx.x;
  float a = za[(size_t)gi * H + j];
  float b = zb[(size_t)gi * H + j];
  feats[j] = a;
  feats[H + j] = b;
  feats[2 * H + j] = fabsf(a - b);
  feats[3 * H + j] = a * b;
  __syncthreads();
  float s = bm1[j];
#pragma unroll 8
  for (int k = 0; k < 4 * H; ++k) s = fmaf(feats[k], Wm1[(size_t)k * H + j], s);
  float hid = fmaxf(s, 0.f);
  red[j] = hid * Wm2[j];
  __syncthreads();
  for (int off = 64; off > 0; off >>= 1) {
    if (j < off) red[j] += red[j + off];
    __syncthreads();
  }
  if (j == 0) out[gi] = red[0] + bm2[0];
}

// ---------------- launch ----------------

extern "C" void kernel_launch(void* const* d_in, const int* in_sizes, int n_in,
                              void* d_out, int out_size, void* d_ws, size_t ws_size,
                              hipStream_t stream) {
  const float* xa = (const float*)d_in[0];
  const int* ei_a = (const int*)d_in[1];
  const int* bv_a = (const int*)d_in[2];
  const float* xb = (const float*)d_in[3];
  const int* ei_b = (const int*)d_in[4];
  const int* bv_b = (const int*)d_in[5];
  const float* W_in = (const float*)d_in[6];
  const float* b_in = (const float*)d_in[7];
  const float* W_c[3] = {(const float*)d_in[8], (const float*)d_in[10], (const float*)d_in[12]};
  const float* b_c[3] = {(const float*)d_in[9], (const float*)d_in[11], (const float*)d_in[13]};
  const float* W_out = (const float*)d_in[14];
  const float* b_out = (const float*)d_in[15];
  const float* W_m1 = (const float*)d_in[16];
  const float* b_m1 = (const float*)d_in[17];
  const float* W_m2 = (const float*)d_in[18];
  const float* b_m2 = (const float*)d_in[19];
  float* out = (float*)d_out;

  char* ws = (char*)d_ws;
  size_t off = 0;
  auto alloc = [&](size_t bytes) -> void* {
    void* p = ws + off;
    off += (bytes + 255) & ~(size_t)255;
    return p;
  };
  float* hA = (float*)alloc((size_t)N * H * 4);
  float* hB = (float*)alloc((size_t)N * H * 4);
  int* deg = (int*)alloc((size_t)N * 4);
  int* rowstart = (int*)alloc((size_t)(N + 1) * 4);
  int* cursor = (int*)alloc((size_t)N * 4);
  int* csr = (int*)alloc((size_t)E * 4);
  float* dinv = (float*)alloc((size_t)N * 4);
  int* bsum = (int*)alloc((size_t)NB * 4);
  int* gstart = (int*)alloc((size_t)(G + 1) * 4);
  float* za = (float*)alloc((size_t)G * H * 4);
  float* zb = (float*)alloc((size_t)G * H * 4);

  for (int side = 0; side < 2; ++side) {
    const float* x = side ? xb : xa;
    const int* src = side ? ei_b : ei_a;
    const int* dst = src + E;
    const int* bv = side ? bv_b : bv_a;
    float* z = side ? zb : za;

    hipMemsetAsync(deg, 0, (size_t)N * 4, stream);
    hist_kernel<<<3125, 256, 0, stream>>>(dst, deg, E);
    blocksum_kernel<<<NB, 256, 0, stream>>>(deg, bsum, N);
    scan_small_kernel<<<1, 1024, 0, stream>>>(bsum, NB, rowstart + N);
    scan_apply_kernel<<<NB, 256, 0, stream>>>(deg, bsum, rowstart, N);
    segstart_kernel<<<782, 256, 0, stream>>>(bv, gstart, N, G);
    prep_kernel<<<782, 256, 0, stream>>>(deg, rowstart, dinv, cursor, N);
    csr_fill_kernel<<<3125, 256, 0, stream>>>(src, dst, cursor, csr, E);
    in_layer_kernel<<<(N * 32 + 255) / 256, 256, 0, stream>>>(x, W_in, b_in, hA, N);
    for (int c = 0; c < 3; ++c) {
      gemm128_kernel<false><<<2048, 256, 0, stream>>>(hA, W_c[c], nullptr, hB, N);
      aggregate_kernel<<<(N * 32 + 255) / 256, 256, 0, stream>>>(hB, dinv, rowstart, csr, b_c[c], hA, N);
    }
    pool_kernel<<<(G * 32) / 256, 256, 0, stream>>>(hA, gstart, hB, G);
    gemm128_kernel<true><<<256, 256, 0, stream>>>(hB, W_out, b_out, z, G);
  }
  classifier_kernel<<<G, 128, 0, stream>>>(za, zb, W_m1, b_m1, W_m2, b_m2, out, G);
}

// Round 3
// 1349.376 us; speedup vs baseline: 1.7159x; 1.2178x over previous
//
#include <hip/hip_runtime.h>
#include <math.h>

constexpr int N = 200000;
constexpr int E = 800000;
constexpr int G = 8192;
constexpr int H = 128;
constexpr int NB = (N + 255) / 256;    // 782 blocks for scan
constexpr int NPAD = 200064;           // 128 * 1563
constexpr int NTILES = NPAD / 128;     // 1563

typedef __attribute__((ext_vector_type(8))) short bf16x8;
typedef __attribute__((ext_vector_type(4))) float f32x4;

__device__ __forceinline__ unsigned short f2bf(float f) {
  unsigned int u = __float_as_uint(f);
  unsigned int r = (u + 0x7FFFu + ((u >> 16) & 1u)) >> 16;
  return (unsigned short)r;
}
__device__ __forceinline__ float bf2f(unsigned short h) {
  return __uint_as_float(((unsigned int)h) << 16);
}

// ---------------- graph-build kernels ----------------

__global__ void hist_kernel(const int* __restrict__ idx, int* __restrict__ cnt, int n) {
  int i = blockIdx.x * blockDim.x + threadIdx.x;
  int stride = gridDim.x * blockDim.x;
  for (; i < n; i += stride) atomicAdd(&cnt[idx[i]], 1);
}

__global__ void blocksum_kernel(const int* __restrict__ in, int* __restrict__ bsum, int n) {
  int i = blockIdx.x * 256 + threadIdx.x;
  int v = (i < n) ? in[i] : 0;
  for (int off = 32; off > 0; off >>= 1) v += __shfl_down(v, off);
  __shared__ int ws[4];
  int lane = threadIdx.x & 63, wv = threadIdx.x >> 6;
  if (lane == 0) ws[wv] = v;
  __syncthreads();
  if (threadIdx.x == 0) bsum[blockIdx.x] = ws[0] + ws[1] + ws[2] + ws[3];
}

__global__ void scan_small_kernel(int* __restrict__ data, int n, int* __restrict__ total_out) {
  __shared__ int buf[1024];
  int t = threadIdx.x;
  int v = (t < n) ? data[t] : 0;
  buf[t] = v;
  __syncthreads();
  for (int off = 1; off < 1024; off <<= 1) {
    int y = (t >= off) ? buf[t - off] : 0;
    __syncthreads();
    buf[t] += y;
    __syncthreads();
  }
  if (t < n) data[t] = buf[t] - v;
  if (t == n - 1) *total_out = buf[t];
}

__global__ void scan_apply_kernel(const int* __restrict__ in, const int* __restrict__ bsum,
                                  int* __restrict__ out, int n) {
  int i = blockIdx.x * 256 + threadIdx.x;
  int v = (i < n) ? in[i] : 0;
  int lane = threadIdx.x & 63, wv = threadIdx.x >> 6;
  int x = v;
  for (int off = 1; off < 64; off <<= 1) {
    int y = __shfl_up(x, off);
    if (lane >= off) x += y;
  }
  __shared__ int ws[4];
  if (lane == 63) ws[wv] = x;
  __syncthreads();
  int woff = 0;
  for (int w = 0; w < wv; ++w) woff += ws[w];
  if (i < n) out[i] = x - v + woff + bsum[blockIdx.x];
}

__global__ void segstart_kernel(const int* __restrict__ bv, int* __restrict__ gstart, int n, int g) {
  int i = blockIdx.x * blockDim.x + threadIdx.x;
  int stride = gridDim.x * blockDim.x;
  for (; i <= n; i += stride) {
    int cur = (i < n) ? bv[i] : g;
    int prev = (i > 0) ? bv[i - 1] : -1;
    for (int q = prev + 1; q <= cur && q <= g; ++q) gstart[q] = i;
  }
}

__global__ void prep_kernel(const int* __restrict__ deg, const int* __restrict__ rowstart,
                            float* __restrict__ dinv, int* __restrict__ cursor, int n) {
  int i = blockIdx.x * blockDim.x + threadIdx.x;
  int stride = gridDim.x * blockDim.x;
  for (; i < n; i += stride) {
    dinv[i] = 1.0f / sqrtf((float)deg[i] + 1.0f);
    cursor[i] = rowstart[i];
  }
}

__global__ void csr_fill_kernel(const int* __restrict__ src, const int* __restrict__ dst,
                                int* __restrict__ cursor, int* __restrict__ csr, int e) {
  int i = blockIdx.x * blockDim.x + threadIdx.x;
  int stride = gridDim.x * blockDim.x;
  for (; i < e; i += stride) {
    int d = dst[i];
    int p = atomicAdd(&cursor[d], 1);
    csr[p] = src[i];
  }
}

// h = relu(x*W_in + b_in) written as bf16 hi/lo pair; 32 lanes per node
__global__ void in_layer_kernel(const float* __restrict__ x, const float* __restrict__ Win,
                                const float* __restrict__ bin,
                                unsigned short* __restrict__ hhi,
                                unsigned short* __restrict__ hlo, int n) {
  int idx = blockIdx.x * blockDim.x + threadIdx.x;
  int node = idx >> 5;
  int lane = idx & 31;
  if (node >= n) return;
  float xv = x[node];
  float4 w = ((const float4*)Win)[lane];
  float4 b = ((const float4*)bin)[lane];
  float v[4];
  v[0] = fmaxf(fmaf(xv, w.x, b.x), 0.f);
  v[1] = fmaxf(fmaf(xv, w.y, b.y), 0.f);
  v[2] = fmaxf(fmaf(xv, w.z, b.z), 0.f);
  v[3] = fmaxf(fmaf(xv, w.w, b.w), 0.f);
  ushort4 hi, lo;
  unsigned short* hp = (unsigned short*)&hi;
  unsigned short* lp = (unsigned short*)&lo;
#pragma unroll
  for (int j = 0; j < 4; ++j) {
    unsigned short h = f2bf(v[j]);
    hp[j] = h;
    lp[j] = f2bf(v[j] - bf2f(h));
  }
  ((ushort4*)hhi)[node * 32 + lane] = hi;
  ((ushort4*)hlo)[node * 32 + lane] = lo;
}

// ---------------- MFMA GEMM: C[NPAD,128] = (Ahi+Alo)[NPAD,128] @ W[128,128] (f32 out) ----------------
// bf16x3: C = Ahi*Whi + Ahi*Wlo + Alo*Whi
__global__ __launch_bounds__(256) void gemm_mfma_kernel(const unsigned short* __restrict__ Ahi,
                                                        const unsigned short* __restrict__ Alo,
                                                        const float* __restrict__ W,
                                                        float* __restrict__ C) {
  __shared__ unsigned short sWhi[16384];  // 32 KiB, W^T layout, XOR-swizzled 16B units
  __shared__ unsigned short sWlo[16384];  // 32 KiB
  int t = threadIdx.x;
  for (int i = t; i < 16384; i += 256) {
    int k = i >> 7, n = i & 127;
    float w = W[i];
    unsigned short hi = f2bf(w);
    unsigned short lo = f2bf(w - bf2f(hi));
    // 16B-unit index: u = n*16 + kg, swizzled: kg ^= (n&7)
    int us = ((n << 4) | ((k >> 3) ^ (n & 7))) * 8 + (k & 7);
    sWhi[us] = hi;
    sWlo[us] = lo;
  }
  __syncthreads();
  int wv = t >> 6, lane = t & 63;
  int lr = lane & 15;        // row (A) / col (B) within fragment
  int lg = lane >> 4;        // k-group 0..3
  int rowbase = blockIdx.x * 128 + wv * 32;
  const bf16x8* Ahi8 = (const bf16x8*)Ahi;
  const bf16x8* Alo8 = (const bf16x8*)Alo;
  f32x4 acc[2][8];
#pragma unroll
  for (int i = 0; i < 2; ++i)
#pragma unroll
    for (int j = 0; j < 8; ++j) acc[i][j] = (f32x4){0.f, 0.f, 0.f, 0.f};
#pragma unroll
  for (int ks = 0; ks < 4; ++ks) {
    bf16x8 ah[2], al[2];
#pragma unroll
    for (int rf = 0; rf < 2; ++rf) {
      int row = rowbase + rf * 16 + lr;
      int idx8 = row * 16 + ks * 4 + lg;
      ah[rf] = Ahi8[idx8];
      al[rf] = Alo8[idx8];
    }
#pragma unroll
    for (int cf = 0; cf < 8; ++cf) {
      int n = (cf << 4) | lr;
      int us8 = ((n << 4) | ((ks * 4 + lg) ^ (n & 7))) * 8;
      bf16x8 wh = *(const bf16x8*)(sWhi + us8);
      bf16x8 wl = *(const bf16x8*)(sWlo + us8);
      acc[0][cf] = __builtin_amdgcn_mfma_f32_16x16x32_bf16(ah[0], wh, acc[0][cf], 0, 0, 0);
      acc[1][cf] = __builtin_amdgcn_mfma_f32_16x16x32_bf16(ah[1], wh, acc[1][cf], 0, 0, 0);
      acc[0][cf] = __builtin_amdgcn_mfma_f32_16x16x32_bf16(ah[0], wl, acc[0][cf], 0, 0, 0);
      acc[1][cf] = __builtin_amdgcn_mfma_f32_16x16x32_bf16(ah[1], wl, acc[1][cf], 0, 0, 0);
      acc[0][cf] = __builtin_amdgcn_mfma_f32_16x16x32_bf16(al[0], wh, acc[0][cf], 0, 0, 0);
      acc[1][cf] = __builtin_amdgcn_mfma_f32_16x16x32_bf16(al[1], wh, acc[1][cf], 0, 0, 0);
    }
  }
  // C/D layout: col = lane&15, row = (lane>>4)*4 + j   [m89-verified]
#pragma unroll
  for (int rf = 0; rf < 2; ++rf) {
#pragma unroll
    for (int cf = 0; cf < 8; ++cf) {
      int r0 = rowbase + rf * 16 + lg * 4;
      int cn = (cf << 4) | lr;
#pragma unroll
      for (int j = 0; j < 4; ++j) C[(r0 + j) * 128 + cn] = acc[rf][cf][j];
    }
  }
}

// out = relu( dn*(sum_in ds*xw[s] + dn*xw[n]) + b ) -> bf16 hi/lo; 32 lanes/node
__global__ __launch_bounds__(256) void aggregate_kernel(const float* __restrict__ xw,
                                                        const float* __restrict__ dinv,
                                                        const int* __restrict__ rowstart,
                                                        const int* __restrict__ csr,
                                                        const float* __restrict__ bias,
                                                        unsigned short* __restrict__ hhi,
                                                        unsigned short* __restrict__ hlo, int n) {
  int idx = blockIdx.x * blockDim.x + threadIdx.x;
  int node = idx >> 5;
  int lane = idx & 31;
  if (node >= n) return;
  const float4* xw4 = (const float4*)xw;
  float dn = dinv[node];
  float4 v = xw4[(size_t)node * 32 + lane];
  float4 acc;
  acc.x = dn * v.x; acc.y = dn * v.y; acc.z = dn * v.z; acc.w = dn * v.w;
  int p0 = rowstart[node], p1 = rowstart[node + 1];
  for (int p = p0; p < p1; ++p) {
    int s = csr[p];
    float ds = dinv[s];
    float4 u = xw4[(size_t)s * 32 + lane];
    acc.x = fmaf(ds, u.x, acc.x);
    acc.y = fmaf(ds, u.y, acc.y);
    acc.z = fmaf(ds, u.z, acc.z);
    acc.w = fmaf(ds, u.w, acc.w);
  }
  float4 b = ((const float4*)bias)[lane];
  float r[4];
  r[0] = fmaxf(fmaf(dn, acc.x, b.x), 0.f);
  r[1] = fmaxf(fmaf(dn, acc.y, b.y), 0.f);
  r[2] = fmaxf(fmaf(dn, acc.z, b.z), 0.f);
  r[3] = fmaxf(fmaf(dn, acc.w, b.w), 0.f);
  ushort4 hi, lo;
  unsigned short* hp = (unsigned short*)&hi;
  unsigned short* lp = (unsigned short*)&lo;
#pragma unroll
  for (int j = 0; j < 4; ++j) {
    unsigned short h = f2bf(r[j]);
    hp[j] = h;
    lp[j] = f2bf(r[j] - bf2f(h));
  }
  ((ushort4*)hhi)[node * 32 + lane] = hi;
  ((ushort4*)hlo)[node * 32 + lane] = lo;
}

// segment-mean pooling from bf16 hi/lo pair: 32 lanes per graph
__global__ void pool_kernel(const unsigned short* __restrict__ hhi,
                            const unsigned short* __restrict__ hlo,
                            const int* __restrict__ gstart,
                            float* __restrict__ pooled, int g) {
  int idx = blockIdx.x * blockDim.x + threadIdx.x;
  int grp = idx >> 5;
  int lane = idx & 31;
  if (grp >= g) return;
  int n0 = gstart[grp], n1 = gstart[grp + 1];
  float4 acc = {0.f, 0.f, 0.f, 0.f};
  for (int nn = n0; nn < n1; ++nn) {
    ushort4 hi = ((const ushort4*)hhi)[(size_t)nn * 32 + lane];
    ushort4 lo = ((const ushort4*)hlo)[(size_t)nn * 32 + lane];
    acc.x += bf2f(hi.x) + bf2f(lo.x);
    acc.y += bf2f(hi.y) + bf2f(lo.y);
    acc.z += bf2f(hi.z) + bf2f(lo.z);
    acc.w += bf2f(hi.w) + bf2f(lo.w);
  }
  float inv = 1.0f / fmaxf((float)(n1 - n0), 1.0f);
  acc.x *= inv; acc.y *= inv; acc.z *= inv; acc.w *= inv;
  ((float4*)pooled)[(size_t)grp * 32 + lane] = acc;
}

// ---------------- small f32 GEMM (pooled @ W_out, bias+relu) ----------------
template <bool EPI>
__global__ __launch_bounds__(256) void gemm128_kernel(const float* __restrict__ A,
                                                      const float* __restrict__ W,
                                                      const float* __restrict__ bias,
                                                      float* __restrict__ C, int rows) {
  __shared__ float sW[H * H];
  __shared__ float sA[32 * H];
  int t = threadIdx.x;
  for (int i = t; i < H * H / 4; i += 256)
    ((float4*)sW)[i] = ((const float4*)W)[i];
  int tr = t >> 5;
  int tc = t & 31;
  float4 bv = {0.f, 0.f, 0.f, 0.f};
  if (EPI) bv = ((const float4*)bias)[tc];
  int ntiles = (rows + 31) >> 5;
  for (int tile = blockIdx.x; tile < ntiles; tile += gridDim.x) {
    int row0 = tile << 5;
    __syncthreads();
    for (int i = t; i < 1024; i += 256) {
      int r = i >> 5, c = i & 31;
      int gr = row0 + r;
      float4 v = {0.f, 0.f, 0.f, 0.f};
      if (gr < rows) v = ((const float4*)A)[(size_t)gr * 32 + c];
      ((float4*)sA)[i] = v;
    }
    __syncthreads();
    float acc[4][4];
#pragma unroll
    for (int i = 0; i < 4; ++i)
#pragma unroll
      for (int j = 0; j < 4; ++j) acc[i][j] = 0.f;
    const float4* sA4 = (const float4*)sA;
    const float4* sW4 = (const float4*)sW;
#pragma unroll 4
    for (int k4 = 0; k4 < 32; ++k4) {
      float4 a0 = sA4[(tr * 4 + 0) * 32 + k4];
      float4 a1 = sA4[(tr * 4 + 1) * 32 + k4];
      float4 a2 = sA4[(tr * 4 + 2) * 32 + k4];
      float4 a3 = sA4[(tr * 4 + 3) * 32 + k4];
      float av[4][4] = {{a0.x, a0.y, a0.z, a0.w},
                        {a1.x, a1.y, a1.z, a1.w},
                        {a2.x, a2.y, a2.z, a2.w},
                        {a3.x, a3.y, a3.z, a3.w}};
#pragma unroll
      for (int kk = 0; kk < 4; ++kk) {
        float4 w = sW4[(k4 * 4 + kk) * 32 + tc];
#pragma unroll
        for (int i = 0; i < 4; ++i) {
          acc[i][0] = fmaf(av[i][kk], w.x, acc[i][0]);
          acc[i][1] = fmaf(av[i][kk], w.y, acc[i][1]);
          acc[i][2] = fmaf(av[i][kk], w.z, acc[i][2]);
          acc[i][3] = fmaf(av[i][kk], w.w, acc[i][3]);
        }
      }
    }
#pragma unroll
    for (int i = 0; i < 4; ++i) {
      int gr = row0 + tr * 4 + i;
      if (gr < rows) {
        float4 r;
        r.x = acc[i][0]; r.y = acc[i][1]; r.z = acc[i][2]; r.w = acc[i][3];
        if (EPI) {
          r.x = fmaxf(r.x + bv.x, 0.f);
          r.y = fmaxf(r.y + bv.y, 0.f);
          r.z = fmaxf(r.z + bv.z, 0.f);
          r.w = fmaxf(r.w + bv.w, 0.f);
        }
        ((float4*)C)[(size_t)gr * 32 + tc] = r;
      }
    }
  }
}

// per-graph MLP head
__global__ __launch_bounds__(128) void classifier_kernel(const float* __restrict__ za,
                                                         const float* __restrict__ zb,
                                                         const float* __restrict__ Wm1,
                                                         const float* __restrict__ bm1,
                                                         const float* __restrict__ Wm2,
                                                         const float* __restrict__ bm2,
                                                         float* __restrict__ out, int g) {
  __shared__ float feats[4 * H];
  __shared__ float red[H];
  int gi = blockIdx.x;
  int j = threadIdx.x;
  float a = za[(size_t)gi * H + j];
  float b = zb[(size_t)gi * H + j];
  feats[j] = a;
  feats[H + j] = b;
  feats[2 * H + j] = fabsf(a - b);
  feats[3 * H + j] = a * b;
  __syncthreads();
  float s = bm1[j];
#pragma unroll 8
  for (int k = 0; k < 4 * H; ++k) s = fmaf(feats[k], Wm1[(size_t)k * H + j], s);
  float hid = fmaxf(s, 0.f);
  red[j] = hid * Wm2[j];
  __syncthreads();
  for (int off = 64; off > 0; off >>= 1) {
    if (j < off) red[j] += red[j + off];
    __syncthreads();
  }
  if (j == 0) out[gi] = red[0] + bm2[0];
}

// ---------------- launch ----------------

extern "C" void kernel_launch(void* const* d_in, const int* in_sizes, int n_in,
                              void* d_out, int out_size, void* d_ws, size_t ws_size,
                              hipStream_t stream) {
  const float* xa = (const float*)d_in[0];
  const int* ei_a = (const int*)d_in[1];
  const int* bv_a = (const int*)d_in[2];
  const float* xb = (const float*)d_in[3];
  const int* ei_b = (const int*)d_in[4];
  const int* bv_b = (const int*)d_in[5];
  const float* W_in = (const float*)d_in[6];
  const float* b_in = (const float*)d_in[7];
  const float* W_c[3] = {(const float*)d_in[8], (const float*)d_in[10], (const float*)d_in[12]};
  const float* b_c[3] = {(const float*)d_in[9], (const float*)d_in[11], (const float*)d_in[13]};
  const float* W_out = (const float*)d_in[14];
  const float* b_out = (const float*)d_in[15];
  const float* W_m1 = (const float*)d_in[16];
  const float* b_m1 = (const float*)d_in[17];
  const float* W_m2 = (const float*)d_in[18];
  const float* b_m2 = (const float*)d_in[19];
  float* out = (float*)d_out;

  char* ws = (char*)d_ws;
  size_t off = 0;
  auto alloc = [&](size_t bytes) -> void* {
    void* p = ws + off;
    off += (bytes + 255) & ~(size_t)255;
    return p;
  };
  float* xw = (float*)alloc((size_t)NPAD * H * 4);          // 102.4 MB
  unsigned short* hhi = (unsigned short*)alloc((size_t)NPAD * H * 2);  // 51.2 MB
  unsigned short* hlo = (unsigned short*)alloc((size_t)NPAD * H * 2);  // 51.2 MB
  int* deg = (int*)alloc((size_t)N * 4);
  int* rowstart = (int*)alloc((size_t)(N + 1) * 4);
  int* cursor = (int*)alloc((size_t)N * 4);
  int* csr = (int*)alloc((size_t)E * 4);
  float* dinv = (float*)alloc((size_t)N * 4);
  int* bsum = (int*)alloc((size_t)NB * 4);
  int* gstart = (int*)alloc((size_t)(G + 1) * 4);
  float* pooled = (float*)alloc((size_t)G * H * 4);
  float* za = (float*)alloc((size_t)G * H * 4);
  float* zb = (float*)alloc((size_t)G * H * 4);

  for (int side = 0; side < 2; ++side) {
    const float* x = side ? xb : xa;
    const int* src = side ? ei_b : ei_a;
    const int* dst = src + E;
    const int* bv = side ? bv_b : bv_a;
    float* z = side ? zb : za;

    hipMemsetAsync(deg, 0, (size_t)N * 4, stream);
    hist_kernel<<<3125, 256, 0, stream>>>(dst, deg, E);
    blocksum_kernel<<<NB, 256, 0, stream>>>(deg, bsum, N);
    scan_small_kernel<<<1, 1024, 0, stream>>>(bsum, NB, rowstart + N);
    scan_apply_kernel<<<NB, 256, 0, stream>>>(deg, bsum, rowstart, N);
    segstart_kernel<<<782, 256, 0, stream>>>(bv, gstart, N, G);
    prep_kernel<<<782, 256, 0, stream>>>(deg, rowstart, dinv, cursor, N);
    csr_fill_kernel<<<3125, 256, 0, stream>>>(src, dst, cursor, csr, E);
    in_layer_kernel<<<(N * 32 + 255) / 256, 256, 0, stream>>>(x, W_in, b_in, hhi, hlo, N);
    for (int c = 0; c < 3; ++c) {
      gemm_mfma_kernel<<<NTILES, 256, 0, stream>>>(hhi, hlo, W_c[c], xw);
      aggregate_kernel<<<(N * 32 + 255) / 256, 256, 0, stream>>>(xw, dinv, rowstart, csr, b_c[c], hhi, hlo, N);
    }
    pool_kernel<<<(G * 32) / 256, 256, 0, stream>>>(hhi, hlo, gstart, pooled, G);
    gemm128_kernel<true><<<256, 256, 0, stream>>>(pooled, W_out, b_out, z, G);
  }
  classifier_kernel<<<G, 128, 0, stream>>>(za, zb, W_m1, b_m1, W_m2, b_m2, out, G);
}

// Round 9
// 1235.292 us; speedup vs baseline: 1.8744x; 1.0924x over previous
//
#include <hip/hip_runtime.h>
#include <math.h>

constexpr int N = 200000;
constexpr int E = 800000;
constexpr int G = 8192;
constexpr int H = 128;
constexpr int NB = (N + 255) / 256;    // 782 blocks for scan
constexpr int NPAD = 200064;           // 128 * 1563
constexpr int NTILES = NPAD / 128;     // 1563
constexpr int GPB = 8;                 // graphs per classifier block

typedef __attribute__((ext_vector_type(8))) short bf16x8;
typedef __attribute__((ext_vector_type(4))) float f32x4;

__device__ __forceinline__ unsigned short f2bf(float f) {
  unsigned int u = __float_as_uint(f);
  unsigned int r = (u + 0x7FFFu + ((u >> 16) & 1u)) >> 16;
  return (unsigned short)r;
}
__device__ __forceinline__ float bf2f(unsigned short h) {
  return __uint_as_float(((unsigned int)h) << 16);
}

// ---------------- graph-build kernels ----------------

__global__ void hist_kernel(const int* __restrict__ idx, int* __restrict__ cnt, int n) {
  int i = blockIdx.x * blockDim.x + threadIdx.x;
  int stride = gridDim.x * blockDim.x;
  for (; i < n; i += stride) atomicAdd(&cnt[idx[i]], 1);
}

__global__ void blocksum_kernel(const int* __restrict__ in, int* __restrict__ bsum, int n) {
  int i = blockIdx.x * 256 + threadIdx.x;
  int v = (i < n) ? in[i] : 0;
  for (int off = 32; off > 0; off >>= 1) v += __shfl_down(v, off);
  __shared__ int ws[4];
  int lane = threadIdx.x & 63, wv = threadIdx.x >> 6;
  if (lane == 0) ws[wv] = v;
  __syncthreads();
  if (threadIdx.x == 0) bsum[blockIdx.x] = ws[0] + ws[1] + ws[2] + ws[3];
}

__global__ void scan_small_kernel(int* __restrict__ data, int n, int* __restrict__ total_out) {
  __shared__ int buf[1024];
  int t = threadIdx.x;
  int v = (t < n) ? data[t] : 0;
  buf[t] = v;
  __syncthreads();
  for (int off = 1; off < 1024; off <<= 1) {
    int y = (t >= off) ? buf[t - off] : 0;
    __syncthreads();
    buf[t] += y;
    __syncthreads();
  }
  if (t < n) data[t] = buf[t] - v;
  if (t == n - 1) *total_out = buf[t];
}

__global__ void scan_apply_kernel(const int* __restrict__ in, const int* __restrict__ bsum,
                                  int* __restrict__ out, int n) {
  int i = blockIdx.x * 256 + threadIdx.x;
  int v = (i < n) ? in[i] : 0;
  int lane = threadIdx.x & 63, wv = threadIdx.x >> 6;
  int x = v;
  for (int off = 1; off < 64; off <<= 1) {
    int y = __shfl_up(x, off);
    if (lane >= off) x += y;
  }
  __shared__ int ws[4];
  if (lane == 63) ws[wv] = x;
  __syncthreads();
  int woff = 0;
  for (int w = 0; w < wv; ++w) woff += ws[w];
  if (i < n) out[i] = x - v + woff + bsum[blockIdx.x];
}

__global__ void segstart_kernel(const int* __restrict__ bv, int* __restrict__ gstart, int n, int g) {
  int i = blockIdx.x * blockDim.x + threadIdx.x;
  int stride = gridDim.x * blockDim.x;
  for (; i <= n; i += stride) {
    int cur = (i < n) ? bv[i] : g;
    int prev = (i > 0) ? bv[i - 1] : -1;
    for (int q = prev + 1; q <= cur && q <= g; ++q) gstart[q] = i;
  }
}

__global__ void prep_kernel(const int* __restrict__ deg, const int* __restrict__ rowstart,
                            float* __restrict__ dinv, int* __restrict__ cursor, int n) {
  int i = blockIdx.x * blockDim.x + threadIdx.x;
  int stride = gridDim.x * blockDim.x;
  for (; i < n; i += stride) {
    dinv[i] = 1.0f / sqrtf((float)deg[i] + 1.0f);
    cursor[i] = rowstart[i];
  }
}

__global__ void csr_fill_kernel(const int* __restrict__ src, const int* __restrict__ dst,
                                int* __restrict__ cursor, int* __restrict__ csr, int e) {
  int i = blockIdx.x * blockDim.x + threadIdx.x;
  int stride = gridDim.x * blockDim.x;
  for (; i < e; i += stride) {
    int d = dst[i];
    int p = atomicAdd(&cursor[d], 1);
    csr[p] = src[i];
  }
}

// h = relu(x*W_in + b_in) written as bf16 hi/lo pair; 32 lanes per node
__global__ void in_layer_kernel(const float* __restrict__ x, const float* __restrict__ Win,
                                const float* __restrict__ bin,
                                unsigned short* __restrict__ hhi,
                                unsigned short* __restrict__ hlo, int n) {
  int idx = blockIdx.x * blockDim.x + threadIdx.x;
  int node = idx >> 5;
  int lane = idx & 31;
  if (node >= n) return;
  float xv = x[node];
  float4 w = ((const float4*)Win)[lane];
  float4 b = ((const float4*)bin)[lane];
  float v[4];
  v[0] = fmaxf(fmaf(xv, w.x, b.x), 0.f);
  v[1] = fmaxf(fmaf(xv, w.y, b.y), 0.f);
  v[2] = fmaxf(fmaf(xv, w.z, b.z), 0.f);
  v[3] = fmaxf(fmaf(xv, w.w, b.w), 0.f);
  ushort4 hi, lo;
  unsigned short* hp = (unsigned short*)&hi;
  unsigned short* lp = (unsigned short*)&lo;
#pragma unroll
  for (int j = 0; j < 4; ++j) {
    unsigned short h = f2bf(v[j]);
    hp[j] = h;
    lp[j] = f2bf(v[j] - bf2f(h));
  }
  ((ushort4*)hhi)[node * 32 + lane] = hi;
  ((ushort4*)hlo)[node * 32 + lane] = lo;
}

// ---------------- MFMA GEMM: C[NPAD,128](bf16) = (Ahi+Alo)[NPAD,128] @ W[128,128] ----------------
// bf16x3: C = Ahi*Whi + Ahi*Wlo + Alo*Whi, f32 accum, rounded to bf16 on store
__global__ __launch_bounds__(256) void gemm_mfma_kernel(const unsigned short* __restrict__ Ahi,
                                                        const unsigned short* __restrict__ Alo,
                                                        const float* __restrict__ W,
                                                        unsigned short* __restrict__ C) {
  __shared__ unsigned short sWhi[16384];  // 32 KiB, W^T layout, XOR-swizzled 16B units
  __shared__ unsigned short sWlo[16384];  // 32 KiB
  int t = threadIdx.x;
  for (int i = t; i < 16384; i += 256) {
    int k = i >> 7, n = i & 127;
    float w = W[i];
    unsigned short hi = f2bf(w);
    unsigned short lo = f2bf(w - bf2f(hi));
    int us = ((n << 4) | ((k >> 3) ^ (n & 7))) * 8 + (k & 7);
    sWhi[us] = hi;
    sWlo[us] = lo;
  }
  __syncthreads();
  int wv = t >> 6, lane = t & 63;
  int lr = lane & 15;        // row (A) / col (B) within fragment
  int lg = lane >> 4;        // k-group 0..3
  int rowbase = blockIdx.x * 128 + wv * 32;
  const bf16x8* Ahi8 = (const bf16x8*)Ahi;
  const bf16x8* Alo8 = (const bf16x8*)Alo;
  f32x4 acc[2][8];
#pragma unroll
  for (int i = 0; i < 2; ++i)
#pragma unroll
    for (int j = 0; j < 8; ++j) acc[i][j] = (f32x4){0.f, 0.f, 0.f, 0.f};
#pragma unroll
  for (int ks = 0; ks < 4; ++ks) {
    bf16x8 ah[2], al[2];
#pragma unroll
    for (int rf = 0; rf < 2; ++rf) {
      int row = rowbase + rf * 16 + lr;
      int idx8 = row * 16 + ks * 4 + lg;
      ah[rf] = Ahi8[idx8];
      al[rf] = Alo8[idx8];
    }
#pragma unroll
    for (int cf = 0; cf < 8; ++cf) {
      int n = (cf << 4) | lr;
      int us8 = ((n << 4) | ((ks * 4 + lg) ^ (n & 7))) * 8;
      bf16x8 wh = *(const bf16x8*)(sWhi + us8);
      bf16x8 wl = *(const bf16x8*)(sWlo + us8);
      acc[0][cf] = __builtin_amdgcn_mfma_f32_16x16x32_bf16(ah[0], wh, acc[0][cf], 0, 0, 0);
      acc[1][cf] = __builtin_amdgcn_mfma_f32_16x16x32_bf16(ah[1], wh, acc[1][cf], 0, 0, 0);
      acc[0][cf] = __builtin_amdgcn_mfma_f32_16x16x32_bf16(ah[0], wl, acc[0][cf], 0, 0, 0);
      acc[1][cf] = __builtin_amdgcn_mfma_f32_16x16x32_bf16(ah[1], wl, acc[1][cf], 0, 0, 0);
      acc[0][cf] = __builtin_amdgcn_mfma_f32_16x16x32_bf16(al[0], wh, acc[0][cf], 0, 0, 0);
      acc[1][cf] = __builtin_amdgcn_mfma_f32_16x16x32_bf16(al[1], wh, acc[1][cf], 0, 0, 0);
    }
  }
  // C/D layout: col = lane&15, row = (lane>>4)*4 + j   [m89-verified]
  // bf16 store: pack col-pairs across adjacent lanes -> dword stores.
  // even lane (col even) stores rows j=0,1; odd lane stores rows j=2,3.
  int even = (lane & 1) == 0;
#pragma unroll
  for (int rf = 0; rf < 2; ++rf) {
#pragma unroll
    for (int cf = 0; cf < 8; ++cf) {
      int r0 = rowbase + rf * 16 + lg * 4;
      int cn = (cf << 4) | lr;
      int colb = cn & ~1;
      unsigned int u0 = f2bf(acc[rf][cf][0]);
      unsigned int u1 = f2bf(acc[rf][cf][1]);
      unsigned int u2 = f2bf(acc[rf][cf][2]);
      unsigned int u3 = f2bf(acc[rf][cf][3]);
      unsigned int p0 = (unsigned int)__shfl_xor((int)u0, 1);
      unsigned int p1 = (unsigned int)__shfl_xor((int)u1, 1);
      unsigned int p2 = (unsigned int)__shfl_xor((int)u2, 1);
      unsigned int p3 = (unsigned int)__shfl_xor((int)u3, 1);
      unsigned int pkA, pkB;
      int rA;
      if (even) { pkA = u0 | (p0 << 16); pkB = u1 | (p1 << 16); rA = r0; }
      else      { pkA = p2 | (u2 << 16); pkB = p3 | (u3 << 16); rA = r0 + 2; }
      *(unsigned int*)(C + (size_t)rA * 128 + colb) = pkA;
      *(unsigned int*)(C + (size_t)(rA + 1) * 128 + colb) = pkB;
    }
  }
}

// out = relu( dn*(sum_in ds*xw[s] + dn*xw[n]) + b ) -> bf16 hi/lo; 32 lanes/node
// xw is bf16 [NPAD][128]
__global__ __launch_bounds__(256) void aggregate_kernel(const unsigned short* __restrict__ xw,
                                                        const float* __restrict__ dinv,
                                                        const int* __restrict__ rowstart,
                                                        const int* __restrict__ csr,
                                                        const float* __restrict__ bias,
                                                        unsigned short* __restrict__ hhi,
                                                        unsigned short* __restrict__ hlo, int n) {
  int idx = blockIdx.x * blockDim.x + threadIdx.x;
  int node = idx >> 5;
  int lane = idx & 31;
  if (node >= n) return;
  const ushort4* xw4 = (const ushort4*)xw;
  float dn = dinv[node];
  ushort4 v = xw4[(size_t)node * 32 + lane];
  float4 acc;
  acc.x = dn * bf2f(v.x); acc.y = dn * bf2f(v.y);
  acc.z = dn * bf2f(v.z); acc.w = dn * bf2f(v.w);
  int p0 = rowstart[node], p1 = rowstart[node + 1];
  for (int p = p0; p < p1; ++p) {
    int s = csr[p];
    float ds = dinv[s];
    ushort4 u = xw4[(size_t)s * 32 + lane];
    acc.x = fmaf(ds, bf2f(u.x), acc.x);
    acc.y = fmaf(ds, bf2f(u.y), acc.y);
    acc.z = fmaf(ds, bf2f(u.z), acc.z);
    acc.w = fmaf(ds, bf2f(u.w), acc.w);
  }
  float4 b = ((const float4*)bias)[lane];
  float r[4];
  r[0] = fmaxf(fmaf(dn, acc.x, b.x), 0.f);
  r[1] = fmaxf(fmaf(dn, acc.y, b.y), 0.f);
  r[2] = fmaxf(fmaf(dn, acc.z, b.z), 0.f);
  r[3] = fmaxf(fmaf(dn, acc.w, b.w), 0.f);
  ushort4 hi, lo;
  unsigned short* hp = (unsigned short*)&hi;
  unsigned short* lp = (unsigned short*)&lo;
#pragma unroll
  for (int j = 0; j < 4; ++j) {
    unsigned short h = f2bf(r[j]);
    hp[j] = h;
    lp[j] = f2bf(r[j] - bf2f(h));
  }
  ((ushort4*)hhi)[node * 32 + lane] = hi;
  ((ushort4*)hlo)[node * 32 + lane] = lo;
}

// segment-mean pooling from bf16 hi/lo pair: 32 lanes per graph
__global__ void pool_kernel(const unsigned short* __restrict__ hhi,
                            const unsigned short* __restrict__ hlo,
                            const int* __restrict__ gstart,
                            float* __restrict__ pooled, int g) {
  int idx = blockIdx.x * blockDim.x + threadIdx.x;
  int grp = idx >> 5;
  int lane = idx & 31;
  if (grp >= g) return;
  int n0 = gstart[grp], n1 = gstart[grp + 1];
  float4 acc = {0.f, 0.f, 0.f, 0.f};
  for (int nn = n0; nn < n1; ++nn) {
    ushort4 hi = ((const ushort4*)hhi)[(size_t)nn * 32 + lane];
    ushort4 lo = ((const ushort4*)hlo)[(size_t)nn * 32 + lane];
    acc.x += bf2f(hi.x) + bf2f(lo.x);
    acc.y += bf2f(hi.y) + bf2f(lo.y);
    acc.z += bf2f(hi.z) + bf2f(lo.z);
    acc.w += bf2f(hi.w) + bf2f(lo.w);
  }
  float inv = 1.0f / fmaxf((float)(n1 - n0), 1.0f);
  acc.x *= inv; acc.y *= inv; acc.z *= inv; acc.w *= inv;
  ((float4*)pooled)[(size_t)grp * 32 + lane] = acc;
}

// ---------------- small f32 GEMM (pooled @ W_out, bias+relu) ----------------
template <bool EPI>
__global__ __launch_bounds__(256) void gemm128_kernel(const float* __restrict__ A,
                                                      const float* __restrict__ W,
                                                      const float* __restrict__ bias,
                                                      float* __restrict__ C, int rows) {
  __shared__ float sW[H * H];
  __shared__ float sA[32 * H];
  int t = threadIdx.x;
  for (int i = t; i < H * H / 4; i += 256)
    ((float4*)sW)[i] = ((const float4*)W)[i];
  int tr = t >> 5;
  int tc = t & 31;
  float4 bv = {0.f, 0.f, 0.f, 0.f};
  if (EPI) bv = ((const float4*)bias)[tc];
  int ntiles = (rows + 31) >> 5;
  for (int tile = blockIdx.x; tile < ntiles; tile += gridDim.x) {
    int row0 = tile << 5;
    __syncthreads();
    for (int i = t; i < 1024; i += 256) {
      int r = i >> 5, c = i & 31;
      int gr = row0 + r;
      float4 v = {0.f, 0.f, 0.f, 0.f};
      if (gr < rows) v = ((const float4*)A)[(size_t)gr * 32 + c];
      ((float4*)sA)[i] = v;
    }
    __syncthreads();
    float acc[4][4];
#pragma unroll
    for (int i = 0; i < 4; ++i)
#pragma unroll
      for (int j = 0; j < 4; ++j) acc[i][j] = 0.f;
    const float4* sA4 = (const float4*)sA;
    const float4* sW4 = (const float4*)sW;
#pragma unroll 4
    for (int k4 = 0; k4 < 32; ++k4) {
      float4 a0 = sA4[(tr * 4 + 0) * 32 + k4];
      float4 a1 = sA4[(tr * 4 + 1) * 32 + k4];
      float4 a2 = sA4[(tr * 4 + 2) * 32 + k4];
      float4 a3 = sA4[(tr * 4 + 3) * 32 + k4];
      float av[4][4] = {{a0.x, a0.y, a0.z, a0.w},
                        {a1.x, a1.y, a1.z, a1.w},
                        {a2.x, a2.y, a2.z, a2.w},
                        {a3.x, a3.y, a3.z, a3.w}};
#pragma unroll
      for (int kk = 0; kk < 4; ++kk) {
        float4 w = sW4[(k4 * 4 + kk) * 32 + tc];
#pragma unroll
        for (int i = 0; i < 4; ++i) {
          acc[i][0] = fmaf(av[i][kk], w.x, acc[i][0]);
          acc[i][1] = fmaf(av[i][kk], w.y, acc[i][1]);
          acc[i][2] = fmaf(av[i][kk], w.z, acc[i][2]);
          acc[i][3] = fmaf(av[i][kk], w.w, acc[i][3]);
        }
      }
    }
#pragma unroll
    for (int i = 0; i < 4; ++i) {
      int gr = row0 + tr * 4 + i;
      if (gr < rows) {
        float4 r;
        r.x = acc[i][0]; r.y = acc[i][1]; r.z = acc[i][2]; r.w = acc[i][3];
        if (EPI) {
          r.x = fmaxf(r.x + bv.x, 0.f);
          r.y = fmaxf(r.y + bv.y, 0.f);
          r.z = fmaxf(r.z + bv.z, 0.f);
          r.w = fmaxf(r.w + bv.w, 0.f);
        }
        ((float4*)C)[(size_t)gr * 32 + tc] = r;
      }
    }
  }
}

// per-graph MLP head: GPB graphs per block, 128 threads
__global__ __launch_bounds__(128) void classifier_kernel(const float* __restrict__ za,
                                                         const float* __restrict__ zb,
                                                         const float* __restrict__ Wm1,
                                                         const float* __restrict__ bm1,
                                                         const float* __restrict__ Wm2,
                                                         const float* __restrict__ bm2,
                                                         float* __restrict__ out, int g) {
  __shared__ float feats[GPB][4 * H];
  __shared__ float part[GPB][2];
  int j = threadIdx.x;
  int g0 = blockIdx.x * GPB;
#pragma unroll
  for (int q = 0; q < GPB; ++q) {
    float a = za[(size_t)(g0 + q) * H + j];
    float b = zb[(size_t)(g0 + q) * H + j];
    feats[q][j] = a;
    feats[q][H + j] = b;
    feats[q][2 * H + j] = fabsf(a - b);
    feats[q][3 * H + j] = a * b;
  }
  __syncthreads();
  float s[GPB];
  float b1 = bm1[j];
#pragma unroll
  for (int q = 0; q < GPB; ++q) s[q] = b1;
#pragma unroll 4
  for (int k = 0; k < 4 * H; ++k) {
    float w = Wm1[(size_t)k * H + j];
#pragma unroll
    for (int q = 0; q < GPB; ++q) s[q] = fmaf(feats[q][k], w, s[q]);
  }
  float w2 = Wm2[j];
  int lane = j & 63, wv = j >> 6;
#pragma unroll
  for (int q = 0; q < GPB; ++q) {
    float v = fmaxf(s[q], 0.f) * w2;
    for (int off = 32; off > 0; off >>= 1) v += __shfl_down(v, off);
    if (lane == 0) part[q][wv] = v;
  }
  __syncthreads();
  if (j < GPB) out[g0 + j] = part[j][0] + part[j][1] + bm2[0];
}

// ---------------- launch ----------------

extern "C" void kernel_launch(void* const* d_in, const int* in_sizes, int n_in,
                              void* d_out, int out_size, void* d_ws, size_t ws_size,
                              hipStream_t stream) {
  const float* xa = (const float*)d_in[0];
  const int* ei_a = (const int*)d_in[1];
  const int* bv_a = (const int*)d_in[2];
  const float* xb = (const float*)d_in[3];
  const int* ei_b = (const int*)d_in[4];
  const int* bv_b = (const int*)d_in[5];
  const float* W_in = (const float*)d_in[6];
  const float* b_in = (const float*)d_in[7];
  const float* W_c[3] = {(const float*)d_in[8], (const float*)d_in[10], (const float*)d_in[12]};
  const float* b_c[3] = {(const float*)d_in[9], (const float*)d_in[11], (const float*)d_in[13]};
  const float* W_out = (const float*)d_in[14];
  const float* b_out = (const float*)d_in[15];
  const float* W_m1 = (const float*)d_in[16];
  const float* b_m1 = (const float*)d_in[17];
  const float* W_m2 = (const float*)d_in[18];
  const float* b_m2 = (const float*)d_in[19];
  float* out = (float*)d_out;

  char* ws = (char*)d_ws;
  size_t off = 0;
  auto alloc = [&](size_t bytes) -> void* {
    void* p = ws + off;
    off += (bytes + 255) & ~(size_t)255;
    return p;
  };
  unsigned short* xwb = (unsigned short*)alloc((size_t)NPAD * H * 2);  // 51.2 MB bf16
  unsigned short* hhi = (unsigned short*)alloc((size_t)NPAD * H * 2);  // 51.2 MB
  unsigned short* hlo = (unsigned short*)alloc((size_t)NPAD * H * 2);  // 51.2 MB
  int* deg = (int*)alloc((size_t)N * 4);
  int* rowstart = (int*)alloc((size_t)(N + 1) * 4);
  int* cursor = (int*)alloc((size_t)N * 4);
  int* csr = (int*)alloc((size_t)E * 4);
  float* dinv = (float*)alloc((size_t)N * 4);
  int* bsum = (int*)alloc((size_t)NB * 4);
  int* gstart = (int*)alloc((size_t)(G + 1) * 4);
  float* pooled = (float*)alloc((size_t)G * H * 4);
  float* za = (float*)alloc((size_t)G * H * 4);
  float* zb = (float*)alloc((size_t)G * H * 4);

  for (int side = 0; side < 2; ++side) {
    const float* x = side ? xb : xa;
    const int* src = side ? ei_b : ei_a;
    const int* dst = src + E;
    const int* bv = side ? bv_b : bv_a;
    float* z = side ? zb : za;

    hipMemsetAsync(deg, 0, (size_t)N * 4, stream);
    hist_kernel<<<3125, 256, 0, stream>>>(dst, deg, E);
    blocksum_kernel<<<NB, 256, 0, stream>>>(deg, bsum, N);
    scan_small_kernel<<<1, 1024, 0, stream>>>(bsum, NB, rowstart + N);
    scan_apply_kernel<<<NB, 256, 0, stream>>>(deg, bsum, rowstart, N);
    segstart_kernel<<<782, 256, 0, stream>>>(bv, gstart, N, G);
    prep_kernel<<<782, 256, 0, stream>>>(deg, rowstart, dinv, cursor, N);
    csr_fill_kernel<<<3125, 256, 0, stream>>>(src, dst, cursor, csr, E);
    in_layer_kernel<<<(N * 32 + 255) / 256, 256, 0, stream>>>(x, W_in, b_in, hhi, hlo, N);
    for (int c = 0; c < 3; ++c) {
      gemm_mfma_kernel<<<NTILES, 256, 0, stream>>>(hhi, hlo, W_c[c], xwb);
      aggregate_kernel<<<(N * 32 + 255) / 256, 256, 0, stream>>>(xwb, dinv, rowstart, csr, b_c[c], hhi, hlo, N);
    }
    pool_kernel<<<(G * 32) / 256, 256, 0, stream>>>(hhi, hlo, gstart, pooled, G);
    gemm128_kernel<true><<<256, 256, 0, stream>>>(pooled, W_out, b_out, z, G);
  }
  classifier_kernel<<<G / GPB, 128, 0, stream>>>(za, zb, W_m1, b_m1, W_m2, b_m2, out, G);
}

// Round 10
// 1201.460 us; speedup vs baseline: 1.9272x; 1.0282x over previous
//
#include <hip/hip_runtime.h>
#include <math.h>

constexpr int N = 200000;
constexpr int E = 800000;
constexpr int G = 8192;
constexpr int H = 128;
constexpr int NB = (N + 255) / 256;    // 782 blocks for scan
constexpr int NPAD = 200064;           // 128 * 1563
constexpr int NTILES = NPAD / 128;     // 1563
constexpr int GPB = 8;                 // graphs per classifier block

typedef __attribute__((ext_vector_type(8))) short bf16x8;
typedef __attribute__((ext_vector_type(4))) float f32x4;

__device__ __forceinline__ unsigned short f2bf(float f) {
  unsigned int u = __float_as_uint(f);
  unsigned int r = (u + 0x7FFFu + ((u >> 16) & 1u)) >> 16;
  return (unsigned short)r;
}
__device__ __forceinline__ float bf2f(unsigned short h) {
  return __uint_as_float(((unsigned int)h) << 16);
}

// ---------------- graph-build (both sides batched per dispatch) ----------------

__global__ void hist2_kernel(const int* __restrict__ dst_a, const int* __restrict__ dst_b,
                             int* __restrict__ deg, int e) {
  int side = blockIdx.x & 1;
  int bid = blockIdx.x >> 1;
  const int* dst = side ? dst_b : dst_a;
  int* cnt = deg + side * N;
  int stride = (gridDim.x >> 1) * 256;
  for (int i = bid * 256 + threadIdx.x; i < e; i += stride) atomicAdd(&cnt[dst[i]], 1);
}

__global__ void blocksum2_kernel(const int* __restrict__ deg, int* __restrict__ bsum) {
  int side = blockIdx.x & 1;
  int b = blockIdx.x >> 1;
  int i = b * 256 + threadIdx.x;
  int v = (i < N) ? deg[side * N + i] : 0;
  for (int off = 32; off > 0; off >>= 1) v += __shfl_down(v, off);
  __shared__ int ws[4];
  int lane = threadIdx.x & 63, wv = threadIdx.x >> 6;
  if (lane == 0) ws[wv] = v;
  __syncthreads();
  if (threadIdx.x == 0) bsum[side * NB + b] = ws[0] + ws[1] + ws[2] + ws[3];
}

// 2 blocks, one per side; exclusive-scans bsum in place; total -> rowstart[side][N]
__global__ void scan_small2_kernel(int* __restrict__ bsum, int* __restrict__ rowstart) {
  int side = blockIdx.x;
  int* data = bsum + side * NB;
  int t = threadIdx.x;
  __shared__ int buf[1024];
  int v = (t < NB) ? data[t] : 0;
  buf[t] = v;
  __syncthreads();
  for (int off = 1; off < 1024; off <<= 1) {
    int y = (t >= off) ? buf[t - off] : 0;
    __syncthreads();
    buf[t] += y;
    __syncthreads();
  }
  if (t < NB) data[t] = buf[t] - v;
  if (t == NB - 1) rowstart[side * (N + 1) + N] = buf[t];
}

// rowstart = exclusive scan of deg; fused prep: dinv + cursor
__global__ void scanapply_prep2_kernel(const int* __restrict__ deg, const int* __restrict__ bsum,
                                       int* __restrict__ rowstart, float* __restrict__ dinv,
                                       int* __restrict__ cursor) {
  int side = blockIdx.x & 1;
  int b = blockIdx.x >> 1;
  int i = b * 256 + threadIdx.x;
  int v = (i < N) ? deg[side * N + i] : 0;
  int lane = threadIdx.x & 63, wv = threadIdx.x >> 6;
  int x = v;
  for (int off = 1; off < 64; off <<= 1) {
    int y = __shfl_up(x, off);
    if (lane >= off) x += y;
  }
  __shared__ int ws[4];
  if (lane == 63) ws[wv] = x;
  __syncthreads();
  int woff = 0;
  for (int w = 0; w < wv; ++w) woff += ws[w];
  if (i < N) {
    int rs = x - v + woff + bsum[side * NB + b];
    rowstart[side * (N + 1) + i] = rs;
    cursor[side * N + i] = rs;
    dinv[side * N + i] = 1.0f / sqrtf((float)v + 1.0f);
  }
}

__global__ void segstart2_kernel(const int* __restrict__ bv_a, const int* __restrict__ bv_b,
                                 int* __restrict__ gstart) {
  int side = blockIdx.x & 1;
  int bid = blockIdx.x >> 1;
  const int* bv = side ? bv_b : bv_a;
  int* gs = gstart + side * (G + 1);
  int stride = (gridDim.x >> 1) * 256;
  for (int i = bid * 256 + threadIdx.x; i <= N; i += stride) {
    int cur = (i < N) ? bv[i] : G;
    int prev = (i > 0) ? bv[i - 1] : -1;
    for (int q = prev + 1; q <= cur && q <= G; ++q) gs[q] = i;
  }
}

__global__ void csrfill2_kernel(const int* __restrict__ ei_a, const int* __restrict__ ei_b,
                                int* __restrict__ cursor, int* __restrict__ csr, int e) {
  int side = blockIdx.x & 1;
  int bid = blockIdx.x >> 1;
  const int* src = side ? ei_b : ei_a;
  const int* dst = src + e;
  int* cur = cursor + side * N;
  int* cs = csr + side * e;
  int stride = (gridDim.x >> 1) * 256;
  for (int i = bid * 256 + threadIdx.x; i < e; i += stride) {
    int d = dst[i];
    int p = atomicAdd(&cur[d], 1);
    cs[p] = src[i];
  }
}

// ---------------- MFMA GEMM: C[NPAD,128](bf16) = A[NPAD,128] @ W[128,128] ----------------
// bf16x3: C = Ahi*Whi + Ahi*Wlo + Alo*Whi, f32 accum, rounded to bf16 on store.
// FUSEIN: A = relu(x*W_in + b_in) computed on the fly (layer 0), bit-identical to
// the old separate in_layer kernel (same fmaf/fmaxf/f2bf sequence).
template <bool FUSEIN>
__global__ __launch_bounds__(256) void gemm_mfma_kernel(const unsigned short* __restrict__ Ahi,
                                                        const unsigned short* __restrict__ Alo,
                                                        const float* __restrict__ X,
                                                        const float* __restrict__ Win,
                                                        const float* __restrict__ bin,
                                                        const float* __restrict__ W,
                                                        unsigned short* __restrict__ C) {
  __shared__ unsigned short sWhi[16384];  // 32 KiB, W^T layout, XOR-swizzled 16B units
  __shared__ unsigned short sWlo[16384];  // 32 KiB
  __shared__ float sWin[H];
  __shared__ float sbin[H];
  int t = threadIdx.x;
  if (FUSEIN) {
    if (t < H) { sWin[t] = Win[t]; sbin[t] = bin[t]; }
  }
  for (int i = t; i < 16384; i += 256) {
    int k = i >> 7, n = i & 127;
    float w = W[i];
    unsigned short hi = f2bf(w);
    unsigned short lo = f2bf(w - bf2f(hi));
    int us = ((n << 4) | ((k >> 3) ^ (n & 7))) * 8 + (k & 7);
    sWhi[us] = hi;
    sWlo[us] = lo;
  }
  __syncthreads();
  int wv = t >> 6, lane = t & 63;
  int lr = lane & 15;        // row (A) / col (B) within fragment
  int lg = lane >> 4;        // k-group 0..3
  int rowbase = blockIdx.x * 128 + wv * 32;
  const bf16x8* Ahi8 = (const bf16x8*)Ahi;
  const bf16x8* Alo8 = (const bf16x8*)Alo;
  f32x4 acc[2][8];
#pragma unroll
  for (int i = 0; i < 2; ++i)
#pragma unroll
    for (int j = 0; j < 8; ++j) acc[i][j] = (f32x4){0.f, 0.f, 0.f, 0.f};
#pragma unroll
  for (int ks = 0; ks < 4; ++ks) {
    bf16x8 ah[2], al[2];
#pragma unroll
    for (int rf = 0; rf < 2; ++rf) {
      int row = rowbase + rf * 16 + lr;
      if (FUSEIN) {
        float xv = (row < N) ? X[row] : 0.f;
        int kbase = (ks * 4 + lg) * 8;
#pragma unroll
        for (int q = 0; q < 8; ++q) {
          float v = fmaxf(fmaf(xv, sWin[kbase + q], sbin[kbase + q]), 0.f);
          unsigned short h = f2bf(v);
          ah[rf][q] = (short)h;
          al[rf][q] = (short)f2bf(v - bf2f(h));
        }
      } else {
        int idx8 = row * 16 + ks * 4 + lg;
        ah[rf] = Ahi8[idx8];
        al[rf] = Alo8[idx8];
      }
    }
#pragma unroll
    for (int cf = 0; cf < 8; ++cf) {
      int n = (cf << 4) | lr;
      int us8 = ((n << 4) | ((ks * 4 + lg) ^ (n & 7))) * 8;
      bf16x8 wh = *(const bf16x8*)(sWhi + us8);
      bf16x8 wl = *(const bf16x8*)(sWlo + us8);
      acc[0][cf] = __builtin_amdgcn_mfma_f32_16x16x32_bf16(ah[0], wh, acc[0][cf], 0, 0, 0);
      acc[1][cf] = __builtin_amdgcn_mfma_f32_16x16x32_bf16(ah[1], wh, acc[1][cf], 0, 0, 0);
      acc[0][cf] = __builtin_amdgcn_mfma_f32_16x16x32_bf16(ah[0], wl, acc[0][cf], 0, 0, 0);
      acc[1][cf] = __builtin_amdgcn_mfma_f32_16x16x32_bf16(ah[1], wl, acc[1][cf], 0, 0, 0);
      acc[0][cf] = __builtin_amdgcn_mfma_f32_16x16x32_bf16(al[0], wh, acc[0][cf], 0, 0, 0);
      acc[1][cf] = __builtin_amdgcn_mfma_f32_16x16x32_bf16(al[1], wh, acc[1][cf], 0, 0, 0);
    }
  }
  // C/D layout: col = lane&15, row = (lane>>4)*4 + j   [m89-verified]
  int even = (lane & 1) == 0;
#pragma unroll
  for (int rf = 0; rf < 2; ++rf) {
#pragma unroll
    for (int cf = 0; cf < 8; ++cf) {
      int r0 = rowbase + rf * 16 + lg * 4;
      int cn = (cf << 4) | lr;
      int colb = cn & ~1;
      unsigned int u0 = f2bf(acc[rf][cf][0]);
      unsigned int u1 = f2bf(acc[rf][cf][1]);
      unsigned int u2 = f2bf(acc[rf][cf][2]);
      unsigned int u3 = f2bf(acc[rf][cf][3]);
      unsigned int p0 = (unsigned int)__shfl_xor((int)u0, 1);
      unsigned int p1 = (unsigned int)__shfl_xor((int)u1, 1);
      unsigned int p2 = (unsigned int)__shfl_xor((int)u2, 1);
      unsigned int p3 = (unsigned int)__shfl_xor((int)u3, 1);
      unsigned int pkA, pkB;
      int rA;
      if (even) { pkA = u0 | (p0 << 16); pkB = u1 | (p1 << 16); rA = r0; }
      else      { pkA = p2 | (u2 << 16); pkB = p3 | (u3 << 16); rA = r0 + 2; }
      *(unsigned int*)(C + (size_t)rA * 128 + colb) = pkA;
      *(unsigned int*)(C + (size_t)(rA + 1) * 128 + colb) = pkB;
    }
  }
}

// out = relu( dn*(sum_in ds*xw[s] + dn*xw[n]) + b ) -> bf16 hi/lo
// 64 lanes/node (uniform edge loop, no intra-wave divergence), 4x edge unroll for MLP.
// Accumulation order per column identical to previous rounds (bit-identical).
__global__ __launch_bounds__(256) void aggregate_kernel(const unsigned short* __restrict__ xw,
                                                        const float* __restrict__ dinv,
                                                        const int* __restrict__ rowstart,
                                                        const int* __restrict__ csr,
                                                        const float* __restrict__ bias,
                                                        unsigned short* __restrict__ hhi,
                                                        unsigned short* __restrict__ hlo, int n) {
  int idx = blockIdx.x * 256 + threadIdx.x;
  int node = idx >> 6;
  int lane = idx & 63;
  if (node >= n) return;
  const unsigned int* xw2 = (const unsigned int*)xw;  // 2 bf16 per dword
  float dn = dinv[node];
  unsigned int v = xw2[(size_t)node * 64 + lane];
  float a0 = dn * bf2f((unsigned short)v);
  float a1 = dn * bf2f((unsigned short)(v >> 16));
  int p0 = rowstart[node], p1 = rowstart[node + 1];
  int p = p0;
  for (; p + 4 <= p1; p += 4) {
    int s0 = csr[p], s1 = csr[p + 1], s2 = csr[p + 2], s3 = csr[p + 3];
    float d0 = dinv[s0], d1 = dinv[s1], d2 = dinv[s2], d3 = dinv[s3];
    unsigned int u0 = xw2[(size_t)s0 * 64 + lane];
    unsigned int u1 = xw2[(size_t)s1 * 64 + lane];
    unsigned int u2 = xw2[(size_t)s2 * 64 + lane];
    unsigned int u3 = xw2[(size_t)s3 * 64 + lane];
    a0 = fmaf(d0, bf2f((unsigned short)u0), a0);
    a1 = fmaf(d0, bf2f((unsigned short)(u0 >> 16)), a1);
    a0 = fmaf(d1, bf2f((unsigned short)u1), a0);
    a1 = fmaf(d1, bf2f((unsigned short)(u1 >> 16)), a1);
    a0 = fmaf(d2, bf2f((unsigned short)u2), a0);
    a1 = fmaf(d2, bf2f((unsigned short)(u2 >> 16)), a1);
    a0 = fmaf(d3, bf2f((unsigned short)u3), a0);
    a1 = fmaf(d3, bf2f((unsigned short)(u3 >> 16)), a1);
  }
  for (; p < p1; ++p) {
    int s = csr[p];
    float ds = dinv[s];
    unsigned int u = xw2[(size_t)s * 64 + lane];
    a0 = fmaf(ds, bf2f((unsigned short)u), a0);
    a1 = fmaf(ds, bf2f((unsigned short)(u >> 16)), a1);
  }
  float2 b = ((const float2*)bias)[lane];
  float r0 = fmaxf(fmaf(dn, a0, b.x), 0.f);
  float r1 = fmaxf(fmaf(dn, a1, b.y), 0.f);
  unsigned short h0 = f2bf(r0), h1 = f2bf(r1);
  unsigned short l0 = f2bf(r0 - bf2f(h0)), l1 = f2bf(r1 - bf2f(h1));
  ((unsigned int*)hhi)[(size_t)node * 64 + lane] = (unsigned int)h0 | ((unsigned int)h1 << 16);
  ((unsigned int*)hlo)[(size_t)node * 64 + lane] = (unsigned int)l0 | ((unsigned int)l1 << 16);
}

// segment-mean pooling from bf16 hi/lo pair: 32 lanes per graph
__global__ void pool_kernel(const unsigned short* __restrict__ hhi,
                            const unsigned short* __restrict__ hlo,
                            const int* __restrict__ gstart,
                            float* __restrict__ pooled, int g) {
  int idx = blockIdx.x * blockDim.x + threadIdx.x;
  int grp = idx >> 5;
  int lane = idx & 31;
  if (grp >= g) return;
  int n0 = gstart[grp], n1 = gstart[grp + 1];
  float4 acc = {0.f, 0.f, 0.f, 0.f};
  for (int nn = n0; nn < n1; ++nn) {
    ushort4 hi = ((const ushort4*)hhi)[(size_t)nn * 32 + lane];
    ushort4 lo = ((const ushort4*)hlo)[(size_t)nn * 32 + lane];
    acc.x += bf2f(hi.x) + bf2f(lo.x);
    acc.y += bf2f(hi.y) + bf2f(lo.y);
    acc.z += bf2f(hi.z) + bf2f(lo.z);
    acc.w += bf2f(hi.w) + bf2f(lo.w);
  }
  float inv = 1.0f / fmaxf((float)(n1 - n0), 1.0f);
  acc.x *= inv; acc.y *= inv; acc.z *= inv; acc.w *= inv;
  ((float4*)pooled)[(size_t)grp * 32 + lane] = acc;
}

// ---------------- small f32 GEMM (pooled[2G] @ W_out, bias+relu) ----------------
template <bool EPI>
__global__ __launch_bounds__(256) void gemm128_kernel(const float* __restrict__ A,
                                                      const float* __restrict__ W,
                                                      const float* __restrict__ bias,
                                                      float* __restrict__ C, int rows) {
  __shared__ float sW[H * H];
  __shared__ float sA[32 * H];
  int t = threadIdx.x;
  for (int i = t; i < H * H / 4; i += 256)
    ((float4*)sW)[i] = ((const float4*)W)[i];
  int tr = t >> 5;
  int tc = t & 31;
  float4 bv = {0.f, 0.f, 0.f, 0.f};
  if (EPI) bv = ((const float4*)bias)[tc];
  int ntiles = (rows + 31) >> 5;
  for (int tile = blockIdx.x; tile < ntiles; tile += gridDim.x) {
    int row0 = tile << 5;
    __syncthreads();
    for (int i = t; i < 1024; i += 256) {
      int r = i >> 5, c = i & 31;
      int gr = row0 + r;
      float4 v = {0.f, 0.f, 0.f, 0.f};
      if (gr < rows) v = ((const float4*)A)[(size_t)gr * 32 + c];
      ((float4*)sA)[i] = v;
    }
    __syncthreads();
    float acc[4][4];
#pragma unroll
    for (int i = 0; i < 4; ++i)
#pragma unroll
      for (int j = 0; j < 4; ++j) acc[i][j] = 0.f;
    const float4* sA4 = (const float4*)sA;
    const float4* sW4 = (const float4*)sW;
#pragma unroll 4
    for (int k4 = 0; k4 < 32; ++k4) {
      float4 a0 = sA4[(tr * 4 + 0) * 32 + k4];
      float4 a1 = sA4[(tr * 4 + 1) * 32 + k4];
      float4 a2 = sA4[(tr * 4 + 2) * 32 + k4];
      float4 a3 = sA4[(tr * 4 + 3) * 32 + k4];
      float av[4][4] = {{a0.x, a0.y, a0.z, a0.w},
                        {a1.x, a1.y, a1.z, a1.w},
                        {a2.x, a2.y, a2.z, a2.w},
                        {a3.x, a3.y, a3.z, a3.w}};
#pragma unroll
      for (int kk = 0; kk < 4; ++kk) {
        float4 w = sW4[(k4 * 4 + kk) * 32 + tc];
#pragma unroll
        for (int i = 0; i < 4; ++i) {
          acc[i][0] = fmaf(av[i][kk], w.x, acc[i][0]);
          acc[i][1] = fmaf(av[i][kk], w.y, acc[i][1]);
          acc[i][2] = fmaf(av[i][kk], w.z, acc[i][2]);
          acc[i][3] = fmaf(av[i][kk], w.w, acc[i][3]);
        }
      }
    }
#pragma unroll
    for (int i = 0; i < 4; ++i) {
      int gr = row0 + tr * 4 + i;
      if (gr < rows) {
        float4 r;
        r.x = acc[i][0]; r.y = acc[i][1]; r.z = acc[i][2]; r.w = acc[i][3];
        if (EPI) {
          r.x = fmaxf(r.x + bv.x, 0.f);
          r.y = fmaxf(r.y + bv.y, 0.f);
          r.z = fmaxf(r.z + bv.z, 0.f);
          r.w = fmaxf(r.w + bv.w, 0.f);
        }
        ((float4*)C)[(size_t)gr * 32 + tc] = r;
      }
    }
  }
}

// per-graph MLP head: GPB graphs per block, 128 threads
__global__ __launch_bounds__(128) void classifier_kernel(const float* __restrict__ za,
                                                         const float* __restrict__ zb,
                                                         const float* __restrict__ Wm1,
                                                         const float* __restrict__ bm1,
                                                         const float* __restrict__ Wm2,
                                                         const float* __restrict__ bm2,
                                                         float* __restrict__ out, int g) {
  __shared__ float feats[GPB][4 * H];
  __shared__ float part[GPB][2];
  int j = threadIdx.x;
  int g0 = blockIdx.x * GPB;
#pragma unroll
  for (int q = 0; q < GPB; ++q) {
    float a = za[(size_t)(g0 + q) * H + j];
    float b = zb[(size_t)(g0 + q) * H + j];
    feats[q][j] = a;
    feats[q][H + j] = b;
    feats[q][2 * H + j] = fabsf(a - b);
    feats[q][3 * H + j] = a * b;
  }
  __syncthreads();
  float s[GPB];
  float b1 = bm1[j];
#pragma unroll
  for (int q = 0; q < GPB; ++q) s[q] = b1;
#pragma unroll 4
  for (int k = 0; k < 4 * H; ++k) {
    float w = Wm1[(size_t)k * H + j];
#pragma unroll
    for (int q = 0; q < GPB; ++q) s[q] = fmaf(feats[q][k], w, s[q]);
  }
  float w2 = Wm2[j];
  int lane = j & 63, wv = j >> 6;
#pragma unroll
  for (int q = 0; q < GPB; ++q) {
    float v = fmaxf(s[q], 0.f) * w2;
    for (int off = 32; off > 0; off >>= 1) v += __shfl_down(v, off);
    if (lane == 0) part[q][wv] = v;
  }
  __syncthreads();
  if (j < GPB) out[g0 + j] = part[j][0] + part[j][1] + bm2[0];
}

// ---------------- launch ----------------

extern "C" void kernel_launch(void* const* d_in, const int* in_sizes, int n_in,
                              void* d_out, int out_size, void* d_ws, size_t ws_size,
                              hipStream_t stream) {
  const float* xa = (const float*)d_in[0];
  const int* ei_a = (const int*)d_in[1];
  const int* bv_a = (const int*)d_in[2];
  const float* xb = (const float*)d_in[3];
  const int* ei_b = (const int*)d_in[4];
  const int* bv_b = (const int*)d_in[5];
  const float* W_in = (const float*)d_in[6];
  const float* b_in = (const float*)d_in[7];
  const float* W_c[3] = {(const float*)d_in[8], (const float*)d_in[10], (const float*)d_in[12]};
  const float* b_c[3] = {(const float*)d_in[9], (const float*)d_in[11], (const float*)d_in[13]};
  const float* W_out = (const float*)d_in[14];
  const float* b_out = (const float*)d_in[15];
  const float* W_m1 = (const float*)d_in[16];
  const float* b_m1 = (const float*)d_in[17];
  const float* W_m2 = (const float*)d_in[18];
  const float* b_m2 = (const float*)d_in[19];
  float* out = (float*)d_out;

  char* ws = (char*)d_ws;
  size_t off = 0;
  auto alloc = [&](size_t bytes) -> void* {
    void* p = ws + off;
    off += (bytes + 255) & ~(size_t)255;
    return p;
  };
  unsigned short* xwb = (unsigned short*)alloc((size_t)NPAD * H * 2);  // 51.2 MB bf16
  unsigned short* hhi = (unsigned short*)alloc((size_t)NPAD * H * 2);  // 51.2 MB
  unsigned short* hlo = (unsigned short*)alloc((size_t)NPAD * H * 2);  // 51.2 MB
  int* deg = (int*)alloc((size_t)2 * N * 4);
  int* rowstart = (int*)alloc((size_t)2 * (N + 1) * 4);
  int* cursor = (int*)alloc((size_t)2 * N * 4);
  int* csr = (int*)alloc((size_t)2 * E * 4);
  float* dinv = (float*)alloc((size_t)2 * N * 4);
  int* bsum = (int*)alloc((size_t)2 * NB * 4);
  int* gstart = (int*)alloc((size_t)2 * (G + 1) * 4);
  float* pooled = (float*)alloc((size_t)2 * G * H * 4);
  float* z = (float*)alloc((size_t)2 * G * H * 4);

  // graph build, both sides batched
  hipMemsetAsync(deg, 0, (size_t)2 * N * 4, stream);
  hist2_kernel<<<6250, 256, 0, stream>>>(ei_a + E, ei_b + E, deg, E);
  blocksum2_kernel<<<2 * NB, 256, 0, stream>>>(deg, bsum);
  scan_small2_kernel<<<2, 1024, 0, stream>>>(bsum, rowstart);
  scanapply_prep2_kernel<<<2 * NB, 256, 0, stream>>>(deg, bsum, rowstart, dinv, cursor);
  segstart2_kernel<<<2 * 782, 256, 0, stream>>>(bv_a, bv_b, gstart);
  csrfill2_kernel<<<6250, 256, 0, stream>>>(ei_a, ei_b, cursor, csr, E);

  for (int side = 0; side < 2; ++side) {
    const float* x = side ? xb : xa;
    const int* rs = rowstart + side * (N + 1);
    const int* cs = csr + side * E;
    const float* dv = dinv + side * N;
    const int* gs = gstart + side * (G + 1);

    // layer 0: in-layer fused into GEMM
    gemm_mfma_kernel<true><<<NTILES, 256, 0, stream>>>(nullptr, nullptr, x, W_in, b_in, W_c[0], xwb);
    aggregate_kernel<<<(N * 64) / 256, 256, 0, stream>>>(xwb, dv, rs, cs, b_c[0], hhi, hlo, N);
    for (int c = 1; c < 3; ++c) {
      gemm_mfma_kernel<false><<<NTILES, 256, 0, stream>>>(hhi, hlo, nullptr, nullptr, nullptr, W_c[c], xwb);
      aggregate_kernel<<<(N * 64) / 256, 256, 0, stream>>>(xwb, dv, rs, cs, b_c[c], hhi, hlo, N);
    }
    pool_kernel<<<(G * 32) / 256, 256, 0, stream>>>(hhi, hlo, gs, pooled + (size_t)side * G * H, G);
  }
  gemm128_kernel<true><<<512, 256, 0, stream>>>(pooled, W_out, b_out, z, 2 * G);
  classifier_kernel<<<G / GPB, 128, 0, stream>>>(z, z + (size_t)G * H, W_m1, b_m1, W_m2, b_m2, out, G);
}

// Round 16
// 1051.290 us; speedup vs baseline: 2.2025x; 1.1428x over previous
//
#include <hip/hip_runtime.h>
#include <math.h>

constexpr int N = 200000;
constexpr int E = 800000;
constexpr int G = 8192;
constexpr int H = 128;
constexpr int NPAD = 200064;           // 128 * 1563
constexpr int NTILES = NPAD / 128;     // 1563
constexpr int GPB = 8;                 // graphs per classifier block
constexpr int NBK = 98;                // buckets per side (2048 nodes each)
constexpr int BKCAP = 10240;           // per-bucket capacity (mean 8163, sigma ~90)
constexpr int ECHUNK = 8192;           // edges per bin-pass block
constexpr int NCH = (E + ECHUNK - 1) / ECHUNK;  // 98

typedef __attribute__((ext_vector_type(8))) short bf16x8;
typedef __attribute__((ext_vector_type(4))) float f32x4;

__device__ __forceinline__ unsigned short f2bf(float f) {
  unsigned int u = __float_as_uint(f);
  unsigned int r = (u + 0x7FFFu + ((u >> 16) & 1u)) >> 16;
  return (unsigned short)r;
}
__device__ __forceinline__ float bf2f(unsigned short h) {
  return __uint_as_float(((unsigned int)h) << 16);
}

// ---------------- graph build: two-pass bucketed CSR ----------------

// pass 1: bin edges by dst>>11; packed entry = (dstLocal<<18)|src
__global__ __launch_bounds__(256) void bin_kernel(const int* __restrict__ ei_a,
                                                  const int* __restrict__ ei_b,
                                                  int* __restrict__ binCnt,
                                                  unsigned int* __restrict__ binned) {
  int side = blockIdx.x & 1;
  int chunk = blockIdx.x >> 1;
  const int* src = side ? ei_b : ei_a;
  const int* dst = src + E;
  int e0 = chunk * ECHUNK;
  int e1 = min(e0 + ECHUNK, E);
  __shared__ int cnt[NBK];
  __shared__ int gbase[NBK];
  int t = threadIdx.x;
  if (t < NBK) cnt[t] = 0;
  __syncthreads();
  for (int i = e0 + t; i < e1; i += 256) atomicAdd(&cnt[dst[i] >> 11], 1);
  __syncthreads();
  if (t < NBK) {
    gbase[t] = atomicAdd(&binCnt[side * NBK + t], cnt[t]);
    cnt[t] = 0;
  }
  __syncthreads();
  for (int i = e0 + t; i < e1; i += 256) {
    int d = dst[i];
    int b = d >> 11;
    int pos = atomicAdd(&cnt[b], 1);
    unsigned int entry = ((unsigned int)(d & 2047) << 18) | (unsigned int)src[i];
    binned[((size_t)(side * NBK + b)) * BKCAP + gbase[b] + pos] = entry;
  }
}

// exclusive scan of bucket counts per side -> bucketBase
__global__ void bucketbase_kernel(const int* __restrict__ binCnt, int* __restrict__ bucketBase) {
  __shared__ int buf[256];
  int t = threadIdx.x;
  for (int side = 0; side < 2; ++side) {
    int v = (t < NBK) ? binCnt[side * NBK + t] : 0;
    buf[t] = v;
    __syncthreads();
    for (int off = 1; off < 256; off <<= 1) {
      int y = (t >= off) ? buf[t - off] : 0;
      __syncthreads();
      buf[t] += y;
      __syncthreads();
    }
    if (t < NBK) bucketBase[side * NBK + t] = buf[t] - v;
    __syncthreads();
  }
}

// pass 2: per (side,bucket): LDS histogram + scan -> rowstart, dinv, csr scatter (LDS cursors)
__global__ __launch_bounds__(256) void csrbuild_kernel(const unsigned int* __restrict__ binned,
                                                       const int* __restrict__ binCnt,
                                                       const int* __restrict__ bucketBase,
                                                       int* __restrict__ rowstart,
                                                       float* __restrict__ dinv,
                                                       int* __restrict__ csr) {
  int side = blockIdx.x & 1;
  int b = blockIdx.x >> 1;
  int t = threadIdx.x;
  __shared__ int hist[2048];
  __shared__ int ws4[4];
  const unsigned int* bin = binned + ((size_t)(side * NBK + b)) * BKCAP;
  int cnt = binCnt[side * NBK + b];
  int base = bucketBase[side * NBK + b];
  int node0 = b << 11;
  int nnodes = min(2048, N - node0);
#pragma unroll
  for (int q = 0; q < 8; ++q) hist[t * 8 + q] = 0;
  __syncthreads();
  for (int k = t; k < cnt; k += 256) atomicAdd(&hist[bin[k] >> 18], 1);
  __syncthreads();
  // scan 2048 histogram entries (8 per thread)
  int c[8], vals[8];
  int s = 0;
#pragma unroll
  for (int q = 0; q < 8; ++q) {
    c[q] = hist[t * 8 + q];
    vals[q] = s;
    s += c[q];
  }
  int lane = t & 63, wv = t >> 6;
  int x = s;
  for (int off = 1; off < 64; off <<= 1) {
    int y = __shfl_up(x, off);
    if (lane >= off) x += y;
  }
  if (lane == 63) ws4[wv] = x;
  __syncthreads();
  int woff = 0;
  for (int w = 0; w < wv; ++w) woff += ws4[w];
  int tbase = x - s + woff;
  __syncthreads();  // all hist reads done before overwrite
#pragma unroll
  for (int q = 0; q < 8; ++q) {
    int j = t * 8 + q;
    int sc = tbase + vals[q];
    hist[j] = sc;  // LDS cursor (local offset)
    if (j < nnodes) {
      rowstart[side * (N + 1) + node0 + j] = base + sc;
      dinv[side * N + node0 + j] = 1.0f / sqrtf((float)c[q] + 1.0f);
    }
  }
  if (b == 0 && t == 0) rowstart[side * (N + 1) + N] = E;
  __syncthreads();
  int* mycsr = csr + (size_t)side * E + base;
  for (int k = t; k < cnt; k += 256) {
    unsigned int e = bin[k];
    int dl = e >> 18;
    int p = atomicAdd(&hist[dl], 1);
    mycsr[p] = (int)(e & 0x3FFFFu);
  }
}

__global__ void segstart2_kernel(const int* __restrict__ bv_a, const int* __restrict__ bv_b,
                                 int* __restrict__ gstart) {
  int side = blockIdx.x & 1;
  int bid = blockIdx.x >> 1;
  const int* bv = side ? bv_b : bv_a;
  int* gs = gstart + side * (G + 1);
  int stride = (gridDim.x >> 1) * 256;
  for (int i = bid * 256 + threadIdx.x; i <= N; i += stride) {
    int cur = (i < N) ? bv[i] : G;
    int prev = (i > 0) ? bv[i - 1] : -1;
    for (int q = prev + 1; q <= cur && q <= G; ++q) gs[q] = i;
  }
}

// ---------------- MFMA GEMM: C[NPAD,128](bf16) = A[NPAD,128] @ W[128,128] ----------------
// bf16x3: C = Ahi*Whi + Ahi*Wlo + Alo*Whi, f32 accum, rounded to bf16 on store.
// FUSEIN: A = relu(x*W_in + b_in) computed on the fly (layer 0).
template <bool FUSEIN>
__global__ __launch_bounds__(256) void gemm_mfma_kernel(const unsigned short* __restrict__ Ahi,
                                                        const unsigned short* __restrict__ Alo,
                                                        const float* __restrict__ X,
                                                        const float* __restrict__ Win,
                                                        const float* __restrict__ bin,
                                                        const float* __restrict__ W,
                                                        unsigned short* __restrict__ C) {
  __shared__ unsigned short sWhi[16384];  // 32 KiB, W^T layout, XOR-swizzled 16B units
  __shared__ unsigned short sWlo[16384];  // 32 KiB
  __shared__ float sWin[H];
  __shared__ float sbin[H];
  int t = threadIdx.x;
  if (FUSEIN) {
    if (t < H) { sWin[t] = Win[t]; sbin[t] = bin[t]; }
  }
  for (int i = t; i < 16384; i += 256) {
    int k = i >> 7, n = i & 127;
    float w = W[i];
    unsigned short hi = f2bf(w);
    unsigned short lo = f2bf(w - bf2f(hi));
    int us = ((n << 4) | ((k >> 3) ^ (n & 7))) * 8 + (k & 7);
    sWhi[us] = hi;
    sWlo[us] = lo;
  }
  __syncthreads();
  int wv = t >> 6, lane = t & 63;
  int lr = lane & 15;
  int lg = lane >> 4;
  int rowbase = blockIdx.x * 128 + wv * 32;
  const bf16x8* Ahi8 = (const bf16x8*)Ahi;
  const bf16x8* Alo8 = (const bf16x8*)Alo;
  f32x4 acc[2][8];
#pragma unroll
  for (int i = 0; i < 2; ++i)
#pragma unroll
    for (int j = 0; j < 8; ++j) acc[i][j] = (f32x4){0.f, 0.f, 0.f, 0.f};
#pragma unroll
  for (int ks = 0; ks < 4; ++ks) {
    bf16x8 ah[2], al[2];
#pragma unroll
    for (int rf = 0; rf < 2; ++rf) {
      int row = rowbase + rf * 16 + lr;
      if (FUSEIN) {
        float xv = (row < N) ? X[row] : 0.f;
        int kbase = (ks * 4 + lg) * 8;
#pragma unroll
        for (int q = 0; q < 8; ++q) {
          float v = fmaxf(fmaf(xv, sWin[kbase + q], sbin[kbase + q]), 0.f);
          unsigned short h = f2bf(v);
          ah[rf][q] = (short)h;
          al[rf][q] = (short)f2bf(v - bf2f(h));
        }
      } else {
        int idx8 = row * 16 + ks * 4 + lg;
        ah[rf] = Ahi8[idx8];
        al[rf] = Alo8[idx8];
      }
    }
#pragma unroll
    for (int cf = 0; cf < 8; ++cf) {
      int n = (cf << 4) | lr;
      int us8 = ((n << 4) | ((ks * 4 + lg) ^ (n & 7))) * 8;
      bf16x8 wh = *(const bf16x8*)(sWhi + us8);
      bf16x8 wl = *(const bf16x8*)(sWlo + us8);
      acc[0][cf] = __builtin_amdgcn_mfma_f32_16x16x32_bf16(ah[0], wh, acc[0][cf], 0, 0, 0);
      acc[1][cf] = __builtin_amdgcn_mfma_f32_16x16x32_bf16(ah[1], wh, acc[1][cf], 0, 0, 0);
      acc[0][cf] = __builtin_amdgcn_mfma_f32_16x16x32_bf16(ah[0], wl, acc[0][cf], 0, 0, 0);
      acc[1][cf] = __builtin_amdgcn_mfma_f32_16x16x32_bf16(ah[1], wl, acc[1][cf], 0, 0, 0);
      acc[0][cf] = __builtin_amdgcn_mfma_f32_16x16x32_bf16(al[0], wh, acc[0][cf], 0, 0, 0);
      acc[1][cf] = __builtin_amdgcn_mfma_f32_16x16x32_bf16(al[1], wh, acc[1][cf], 0, 0, 0);
    }
  }
  // C/D layout: col = lane&15, row = (lane>>4)*4 + j   [m89-verified]
  int even = (lane & 1) == 0;
#pragma unroll
  for (int rf = 0; rf < 2; ++rf) {
#pragma unroll
    for (int cf = 0; cf < 8; ++cf) {
      int r0 = rowbase + rf * 16 + lg * 4;
      int cn = (cf << 4) | lr;
      int colb = cn & ~1;
      unsigned int u0 = f2bf(acc[rf][cf][0]);
      unsigned int u1 = f2bf(acc[rf][cf][1]);
      unsigned int u2 = f2bf(acc[rf][cf][2]);
      unsigned int u3 = f2bf(acc[rf][cf][3]);
      unsigned int p0 = (unsigned int)__shfl_xor((int)u0, 1);
      unsigned int p1 = (unsigned int)__shfl_xor((int)u1, 1);
      unsigned int p2 = (unsigned int)__shfl_xor((int)u2, 1);
      unsigned int p3 = (unsigned int)__shfl_xor((int)u3, 1);
      unsigned int pkA, pkB;
      int rA;
      if (even) { pkA = u0 | (p0 << 16); pkB = u1 | (p1 << 16); rA = r0; }
      else      { pkA = p2 | (u2 << 16); pkB = p3 | (u3 << 16); rA = r0 + 2; }
      *(unsigned int*)(C + (size_t)rA * 128 + colb) = pkA;
      *(unsigned int*)(C + (size_t)(rA + 1) * 128 + colb) = pkB;
    }
  }
}

// out = relu( dn*(sum_in ds*xw[s] + dn*xw[n]) + b ) -> bf16 hi/lo; 64 lanes/node, 4x unroll
__global__ __launch_bounds__(256) void aggregate_kernel(const unsigned short* __restrict__ xw,
                                                        const float* __restrict__ dinv,
                                                        const int* __restrict__ rowstart,
                                                        const int* __restrict__ csr,
                                                        const float* __restrict__ bias,
                                                        unsigned short* __restrict__ hhi,
                                                        unsigned short* __restrict__ hlo, int n) {
  int idx = blockIdx.x * 256 + threadIdx.x;
  int node = idx >> 6;
  int lane = idx & 63;
  if (node >= n) return;
  const unsigned int* xw2 = (const unsigned int*)xw;
  float dn = dinv[node];
  unsigned int v = xw2[(size_t)node * 64 + lane];
  float a0 = dn * bf2f((unsigned short)v);
  float a1 = dn * bf2f((unsigned short)(v >> 16));
  int p0 = rowstart[node], p1 = rowstart[node + 1];
  int p = p0;
  for (; p + 4 <= p1; p += 4) {
    int s0 = csr[p], s1 = csr[p + 1], s2 = csr[p + 2], s3 = csr[p + 3];
    float d0 = dinv[s0], d1 = dinv[s1], d2 = dinv[s2], d3 = dinv[s3];
    unsigned int u0 = xw2[(size_t)s0 * 64 + lane];
    unsigned int u1 = xw2[(size_t)s1 * 64 + lane];
    unsigned int u2 = xw2[(size_t)s2 * 64 + lane];
    unsigned int u3 = xw2[(size_t)s3 * 64 + lane];
    a0 = fmaf(d0, bf2f((unsigned short)u0), a0);
    a1 = fmaf(d0, bf2f((unsigned short)(u0 >> 16)), a1);
    a0 = fmaf(d1, bf2f((unsigned short)u1), a0);
    a1 = fmaf(d1, bf2f((unsigned short)(u1 >> 16)), a1);
    a0 = fmaf(d2, bf2f((unsigned short)u2), a0);
    a1 = fmaf(d2, bf2f((unsigned short)(u2 >> 16)), a1);
    a0 = fmaf(d3, bf2f((unsigned short)u3), a0);
    a1 = fmaf(d3, bf2f((unsigned short)(u3 >> 16)), a1);
  }
  for (; p < p1; ++p) {
    int s = csr[p];
    float ds = dinv[s];
    unsigned int u = xw2[(size_t)s * 64 + lane];
    a0 = fmaf(ds, bf2f((unsigned short)u), a0);
    a1 = fmaf(ds, bf2f((unsigned short)(u >> 16)), a1);
  }
  float2 b = ((const float2*)bias)[lane];
  float r0 = fmaxf(fmaf(dn, a0, b.x), 0.f);
  float r1 = fmaxf(fmaf(dn, a1, b.y), 0.f);
  unsigned short h0 = f2bf(r0), h1 = f2bf(r1);
  unsigned short l0 = f2bf(r0 - bf2f(h0)), l1 = f2bf(r1 - bf2f(h1));
  ((unsigned int*)hhi)[(size_t)node * 64 + lane] = (unsigned int)h0 | ((unsigned int)h1 << 16);
  ((unsigned int*)hlo)[(size_t)node * 64 + lane] = (unsigned int)l0 | ((unsigned int)l1 << 16);
}

// segment-mean pooling from bf16 hi/lo pair: 32 lanes per graph
__global__ void pool_kernel(const unsigned short* __restrict__ hhi,
                            const unsigned short* __restrict__ hlo,
                            const int* __restrict__ gstart,
                            float* __restrict__ pooled, int g) {
  int idx = blockIdx.x * blockDim.x + threadIdx.x;
  int grp = idx >> 5;
  int lane = idx & 31;
  if (grp >= g) return;
  int n0 = gstart[grp], n1 = gstart[grp + 1];
  float4 acc = {0.f, 0.f, 0.f, 0.f};
  for (int nn = n0; nn < n1; ++nn) {
    ushort4 hi = ((const ushort4*)hhi)[(size_t)nn * 32 + lane];
    ushort4 lo = ((const ushort4*)hlo)[(size_t)nn * 32 + lane];
    acc.x += bf2f(hi.x) + bf2f(lo.x);
    acc.y += bf2f(hi.y) + bf2f(lo.y);
    acc.z += bf2f(hi.z) + bf2f(lo.z);
    acc.w += bf2f(hi.w) + bf2f(lo.w);
  }
  float inv = 1.0f / fmaxf((float)(n1 - n0), 1.0f);
  acc.x *= inv; acc.y *= inv; acc.z *= inv; acc.w *= inv;
  ((float4*)pooled)[(size_t)grp * 32 + lane] = acc;
}

// ---------------- small f32 GEMM (pooled[2G] @ W_out, bias+relu) ----------------
template <bool EPI>
__global__ __launch_bounds__(256) void gemm128_kernel(const float* __restrict__ A,
                                                      const float* __restrict__ W,
                                                      const float* __restrict__ bias,
                                                      float* __restrict__ C, int rows) {
  __shared__ float sW[H * H];
  __shared__ float sA[32 * H];
  int t = threadIdx.x;
  for (int i = t; i < H * H / 4; i += 256)
    ((float4*)sW)[i] = ((const float4*)W)[i];
  int tr = t >> 5;
  int tc = t & 31;
  float4 bv = {0.f, 0.f, 0.f, 0.f};
  if (EPI) bv = ((const float4*)bias)[tc];
  int ntiles = (rows + 31) >> 5;
  for (int tile = blockIdx.x; tile < ntiles; tile += gridDim.x) {
    int row0 = tile << 5;
    __syncthreads();
    for (int i = t; i < 1024; i += 256) {
      int r = i >> 5, c = i & 31;
      int gr = row0 + r;
      float4 v = {0.f, 0.f, 0.f, 0.f};
      if (gr < rows) v = ((const float4*)A)[(size_t)gr * 32 + c];
      ((float4*)sA)[i] = v;
    }
    __syncthreads();
    float acc[4][4];
#pragma unroll
    for (int i = 0; i < 4; ++i)
#pragma unroll
      for (int j = 0; j < 4; ++j) acc[i][j] = 0.f;
    const float4* sA4 = (const float4*)sA;
    const float4* sW4 = (const float4*)sW;
#pragma unroll 4
    for (int k4 = 0; k4 < 32; ++k4) {
      float4 a0 = sA4[(tr * 4 + 0) * 32 + k4];
      float4 a1 = sA4[(tr * 4 + 1) * 32 + k4];
      float4 a2 = sA4[(tr * 4 + 2) * 32 + k4];
      float4 a3 = sA4[(tr * 4 + 3) * 32 + k4];
      float av[4][4] = {{a0.x, a0.y, a0.z, a0.w},
                        {a1.x, a1.y, a1.z, a1.w},
                        {a2.x, a2.y, a2.z, a2.w},
                        {a3.x, a3.y, a3.z, a3.w}};
#pragma unroll
      for (int kk = 0; kk < 4; ++kk) {
        float4 w = sW4[(k4 * 4 + kk) * 32 + tc];
#pragma unroll
        for (int i = 0; i < 4; ++i) {
          acc[i][0] = fmaf(av[i][kk], w.x, acc[i][0]);
          acc[i][1] = fmaf(av[i][kk], w.y, acc[i][1]);
          acc[i][2] = fmaf(av[i][kk], w.z, acc[i][2]);
          acc[i][3] = fmaf(av[i][kk], w.w, acc[i][3]);
        }
      }
    }
#pragma unroll
    for (int i = 0; i < 4; ++i) {
      int gr = row0 + tr * 4 + i;
      if (gr < rows) {
        float4 r;
        r.x = acc[i][0]; r.y = acc[i][1]; r.z = acc[i][2]; r.w = acc[i][3];
        if (EPI) {
          r.x = fmaxf(r.x + bv.x, 0.f);
          r.y = fmaxf(r.y + bv.y, 0.f);
          r.z = fmaxf(r.z + bv.z, 0.f);
          r.w = fmaxf(r.w + bv.w, 0.f);
        }
        ((float4*)C)[(size_t)gr * 32 + tc] = r;
      }
    }
  }
}

// per-graph MLP head: GPB graphs per block, 128 threads
__global__ __launch_bounds__(128) void classifier_kernel(const float* __restrict__ za,
                                                         const float* __restrict__ zb,
                                                         const float* __restrict__ Wm1,
                                                         const float* __restrict__ bm1,
                                                         const float* __restrict__ Wm2,
                                                         const float* __restrict__ bm2,
                                                         float* __restrict__ out, int g) {
  __shared__ float feats[GPB][4 * H];
  __shared__ float part[GPB][2];
  int j = threadIdx.x;
  int g0 = blockIdx.x * GPB;
#pragma unroll
  for (int q = 0; q < GPB; ++q) {
    float a = za[(size_t)(g0 + q) * H + j];
    float b = zb[(size_t)(g0 + q) * H + j];
    feats[q][j] = a;
    feats[q][H + j] = b;
    feats[q][2 * H + j] = fabsf(a - b);
    feats[q][3 * H + j] = a * b;
  }
  __syncthreads();
  float s[GPB];
  float b1 = bm1[j];
#pragma unroll
  for (int q = 0; q < GPB; ++q) s[q] = b1;
#pragma unroll 4
  for (int k = 0; k < 4 * H; ++k) {
    float w = Wm1[(size_t)k * H + j];
#pragma unroll
    for (int q = 0; q < GPB; ++q) s[q] = fmaf(feats[q][k], w, s[q]);
  }
  float w2 = Wm2[j];
  int lane = j & 63, wv = j >> 6;
#pragma unroll
  for (int q = 0; q < GPB; ++q) {
    float v = fmaxf(s[q], 0.f) * w2;
    for (int off = 32; off > 0; off >>= 1) v += __shfl_down(v, off);
    if (lane == 0) part[q][wv] = v;
  }
  __syncthreads();
  if (j < GPB) out[g0 + j] = part[j][0] + part[j][1] + bm2[0];
}

// ---------------- launch ----------------

extern "C" void kernel_launch(void* const* d_in, const int* in_sizes, int n_in,
                              void* d_out, int out_size, void* d_ws, size_t ws_size,
                              hipStream_t stream) {
  const float* xa = (const float*)d_in[0];
  const int* ei_a = (const int*)d_in[1];
  const int* bv_a = (const int*)d_in[2];
  const float* xb = (const float*)d_in[3];
  const int* ei_b = (const int*)d_in[4];
  const int* bv_b = (const int*)d_in[5];
  const float* W_in = (const float*)d_in[6];
  const float* b_in = (const float*)d_in[7];
  const float* W_c[3] = {(const float*)d_in[8], (const float*)d_in[10], (const float*)d_in[12]};
  const float* b_c[3] = {(const float*)d_in[9], (const float*)d_in[11], (const float*)d_in[13]};
  const float* W_out = (const float*)d_in[14];
  const float* b_out = (const float*)d_in[15];
  const float* W_m1 = (const float*)d_in[16];
  const float* b_m1 = (const float*)d_in[17];
  const float* W_m2 = (const float*)d_in[18];
  const float* b_m2 = (const float*)d_in[19];
  float* out = (float*)d_out;

  char* ws = (char*)d_ws;
  size_t off = 0;
  auto alloc = [&](size_t bytes) -> void* {
    void* p = ws + off;
    off += (bytes + 255) & ~(size_t)255;
    return p;
  };
  unsigned short* xwb = (unsigned short*)alloc((size_t)NPAD * H * 2);  // 51.2 MB bf16
  unsigned short* hhi = (unsigned short*)alloc((size_t)NPAD * H * 2);  // 51.2 MB
  unsigned short* hlo = (unsigned short*)alloc((size_t)NPAD * H * 2);  // 51.2 MB
  unsigned int* binned = (unsigned int*)alloc((size_t)2 * NBK * BKCAP * 4);  // 8 MB
  int* binCnt = (int*)alloc((size_t)2 * NBK * 4);
  int* bucketBase = (int*)alloc((size_t)2 * NBK * 4);
  int* rowstart = (int*)alloc((size_t)2 * (N + 1) * 4);
  int* csr = (int*)alloc((size_t)2 * E * 4);
  float* dinv = (float*)alloc((size_t)2 * N * 4);
  int* gstart = (int*)alloc((size_t)2 * (G + 1) * 4);
  float* pooled = (float*)alloc((size_t)2 * G * H * 4);
  float* z = (float*)alloc((size_t)2 * G * H * 4);

  // graph build: bucketed two-pass CSR (both sides batched)
  hipMemsetAsync(binCnt, 0, (size_t)2 * NBK * 4, stream);
  bin_kernel<<<2 * NCH, 256, 0, stream>>>(ei_a, ei_b, binCnt, binned);
  bucketbase_kernel<<<1, 256, 0, stream>>>(binCnt, bucketBase);
  csrbuild_kernel<<<2 * NBK, 256, 0, stream>>>(binned, binCnt, bucketBase, rowstart, dinv, csr);
  segstart2_kernel<<<2 * 782, 256, 0, stream>>>(bv_a, bv_b, gstart);

  for (int side = 0; side < 2; ++side) {
    const float* x = side ? xb : xa;
    const int* rs = rowstart + side * (N + 1);
    const int* cs = csr + (size_t)side * E;
    const float* dv = dinv + side * N;
    const int* gs = gstart + side * (G + 1);

    // layer 0: in-layer fused into GEMM
    gemm_mfma_kernel<true><<<NTILES, 256, 0, stream>>>(nullptr, nullptr, x, W_in, b_in, W_c[0], xwb);
    aggregate_kernel<<<(N * 64) / 256, 256, 0, stream>>>(xwb, dv, rs, cs, b_c[0], hhi, hlo, N);
    for (int c = 1; c < 3; ++c) {
      gemm_mfma_kernel<false><<<NTILES, 256, 0, stream>>>(hhi, hlo, nullptr, nullptr, nullptr, W_c[c], xwb);
      aggregate_kernel<<<(N * 64) / 256, 256, 0, stream>>>(xwb, dv, rs, cs, b_c[c], hhi, hlo, N);
    }
    pool_kernel<<<(G * 32) / 256, 256, 0, stream>>>(hhi, hlo, gs, pooled + (size_t)side * G * H, G);
  }
  gemm128_kernel<true><<<512, 256, 0, stream>>>(pooled, W_out, b_out, z, 2 * G);
  classifier_kernel<<<G / GPB, 128, 0, stream>>>(z, z + (size_t)G * H, W_m1, b_m1, W_m2, b_m2, out, G);
}

// Round 17
// 938.160 us; speedup vs baseline: 2.4681x; 1.1206x over previous
//
#include <hip/hip_runtime.h>
#include <math.h>

constexpr int N = 200000;
constexpr int E = 800000;
constexpr int G = 8192;
constexpr int H = 128;
constexpr int NPAD = 200064;           // 128 * 1563
constexpr int NTILES = NPAD / 128;     // 1563
constexpr int GPB = 8;                 // graphs per classifier block
constexpr int NBK = 98;                // buckets per side (2048 nodes each)
constexpr int BKCAP = 10240;           // per-bucket capacity (mean 8163, sigma ~90)
constexpr int ECHUNK = 8192;           // edges per bin-pass block
constexpr int NCH = (E + ECHUNK - 1) / ECHUNK;  // 98
constexpr int AGGB = (N * 64) / 256;   // 50000 aggregate blocks per side

typedef __attribute__((ext_vector_type(8))) short bf16x8;
typedef __attribute__((ext_vector_type(4))) float f32x4;

__device__ __forceinline__ unsigned short f2bf(float f) {
  unsigned int u = __float_as_uint(f);
  unsigned int r = (u + 0x7FFFu + ((u >> 16) & 1u)) >> 16;
  return (unsigned short)r;
}
__device__ __forceinline__ float bf2f(unsigned short h) {
  return __uint_as_float(((unsigned int)h) << 16);
}

// ---------------- graph build: two-pass bucketed CSR ----------------

__global__ __launch_bounds__(256) void bin_kernel(const int* __restrict__ ei_a,
                                                  const int* __restrict__ ei_b,
                                                  int* __restrict__ binCnt,
                                                  unsigned int* __restrict__ binned) {
  int side = blockIdx.x & 1;
  int chunk = blockIdx.x >> 1;
  const int* src = side ? ei_b : ei_a;
  const int* dst = src + E;
  int e0 = chunk * ECHUNK;
  int e1 = min(e0 + ECHUNK, E);
  __shared__ int cnt[NBK];
  __shared__ int gbase[NBK];
  int t = threadIdx.x;
  if (t < NBK) cnt[t] = 0;
  __syncthreads();
  for (int i = e0 + t; i < e1; i += 256) atomicAdd(&cnt[dst[i] >> 11], 1);
  __syncthreads();
  if (t < NBK) {
    gbase[t] = atomicAdd(&binCnt[side * NBK + t], cnt[t]);
    cnt[t] = 0;
  }
  __syncthreads();
  for (int i = e0 + t; i < e1; i += 256) {
    int d = dst[i];
    int b = d >> 11;
    int pos = atomicAdd(&cnt[b], 1);
    unsigned int entry = ((unsigned int)(d & 2047) << 18) | (unsigned int)src[i];
    binned[((size_t)(side * NBK + b)) * BKCAP + gbase[b] + pos] = entry;
  }
}

__global__ void bucketbase_kernel(const int* __restrict__ binCnt, int* __restrict__ bucketBase) {
  __shared__ int buf[256];
  int t = threadIdx.x;
  for (int side = 0; side < 2; ++side) {
    int v = (t < NBK) ? binCnt[side * NBK + t] : 0;
    buf[t] = v;
    __syncthreads();
    for (int off = 1; off < 256; off <<= 1) {
      int y = (t >= off) ? buf[t - off] : 0;
      __syncthreads();
      buf[t] += y;
      __syncthreads();
    }
    if (t < NBK) bucketBase[side * NBK + t] = buf[t] - v;
    __syncthreads();
  }
}

__global__ __launch_bounds__(256) void csrbuild_kernel(const unsigned int* __restrict__ binned,
                                                       const int* __restrict__ binCnt,
                                                       const int* __restrict__ bucketBase,
                                                       int* __restrict__ rowstart,
                                                       float* __restrict__ dinv,
                                                       int* __restrict__ csr) {
  int side = blockIdx.x & 1;
  int b = blockIdx.x >> 1;
  int t = threadIdx.x;
  __shared__ int hist[2048];
  __shared__ int ws4[4];
  const unsigned int* bin = binned + ((size_t)(side * NBK + b)) * BKCAP;
  int cnt = binCnt[side * NBK + b];
  int base = bucketBase[side * NBK + b];
  int node0 = b << 11;
  int nnodes = min(2048, N - node0);
#pragma unroll
  for (int q = 0; q < 8; ++q) hist[t * 8 + q] = 0;
  __syncthreads();
  for (int k = t; k < cnt; k += 256) atomicAdd(&hist[bin[k] >> 18], 1);
  __syncthreads();
  int c[8], vals[8];
  int s = 0;
#pragma unroll
  for (int q = 0; q < 8; ++q) {
    c[q] = hist[t * 8 + q];
    vals[q] = s;
    s += c[q];
  }
  int lane = t & 63, wv = t >> 6;
  int x = s;
  for (int off = 1; off < 64; off <<= 1) {
    int y = __shfl_up(x, off);
    if (lane >= off) x += y;
  }
  if (lane == 63) ws4[wv] = x;
  __syncthreads();
  int woff = 0;
  for (int w = 0; w < wv; ++w) woff += ws4[w];
  int tbase = x - s + woff;
  __syncthreads();
#pragma unroll
  for (int q = 0; q < 8; ++q) {
    int j = t * 8 + q;
    int sc = tbase + vals[q];
    hist[j] = sc;
    if (j < nnodes) {
      rowstart[side * (N + 1) + node0 + j] = base + sc;
      dinv[side * N + node0 + j] = 1.0f / sqrtf((float)c[q] + 1.0f);
    }
  }
  if (b == 0 && t == 0) rowstart[side * (N + 1) + N] = E;
  __syncthreads();
  int* mycsr = csr + (size_t)side * E + base;
  for (int k = t; k < cnt; k += 256) {
    unsigned int e = bin[k];
    int dl = e >> 18;
    int p = atomicAdd(&hist[dl], 1);
    mycsr[p] = (int)(e & 0x3FFFFu);
  }
}

__global__ void segstart2_kernel(const int* __restrict__ bv_a, const int* __restrict__ bv_b,
                                 int* __restrict__ gstart) {
  int side = blockIdx.x & 1;
  int bid = blockIdx.x >> 1;
  const int* bv = side ? bv_b : bv_a;
  int* gs = gstart + side * (G + 1);
  int stride = (gridDim.x >> 1) * 256;
  for (int i = bid * 256 + threadIdx.x; i <= N; i += stride) {
    int cur = (i < N) ? bv[i] : G;
    int prev = (i > 0) ? bv[i - 1] : -1;
    for (int q = prev + 1; q <= cur && q <= G; ++q) gs[q] = i;
  }
}

// ---------------- MFMA GEMM (both sides): C[2][NPAD][128](bf16) = A @ W ----------------
// bf16x2: C = Ah*Whi + Ah*Wlo (A single bf16, W split hi/lo), f32 accum.
// FUSEIN: A = relu(x*W_in + b_in) computed on the fly (layer 0).
template <bool FUSEIN>
__global__ __launch_bounds__(256) void gemm_mfma_kernel(const unsigned short* __restrict__ Ah,
                                                        const float* __restrict__ Xa,
                                                        const float* __restrict__ Xb,
                                                        const float* __restrict__ Win,
                                                        const float* __restrict__ bin,
                                                        const float* __restrict__ W,
                                                        unsigned short* __restrict__ C) {
  __shared__ unsigned short sWhi[16384];  // 32 KiB, W^T layout, XOR-swizzled 16B units
  __shared__ unsigned short sWlo[16384];  // 32 KiB
  __shared__ float sWin[H];
  __shared__ float sbin[H];
  int t = threadIdx.x;
  if (FUSEIN) {
    if (t < H) { sWin[t] = Win[t]; sbin[t] = bin[t]; }
  }
  for (int i = t; i < 16384; i += 256) {
    int k = i >> 7, n = i & 127;
    float w = W[i];
    unsigned short hi = f2bf(w);
    unsigned short lo = f2bf(w - bf2f(hi));
    int us = ((n << 4) | ((k >> 3) ^ (n & 7))) * 8 + (k & 7);
    sWhi[us] = hi;
    sWlo[us] = lo;
  }
  __syncthreads();
  int side = (blockIdx.x >= NTILES) ? 1 : 0;
  int tile = blockIdx.x - side * NTILES;
  const float* X = side ? Xb : Xa;
  int wv = t >> 6, lane = t & 63;
  int lr = lane & 15;
  int lg = lane >> 4;
  int rowbase = tile * 128 + wv * 32;
  const bf16x8* A8 = (const bf16x8*)(Ah + (size_t)side * NPAD * H);
  unsigned short* Cs = C + (size_t)side * NPAD * H;
  f32x4 acc[2][8];
#pragma unroll
  for (int i = 0; i < 2; ++i)
#pragma unroll
    for (int j = 0; j < 8; ++j) acc[i][j] = (f32x4){0.f, 0.f, 0.f, 0.f};
#pragma unroll
  for (int ks = 0; ks < 4; ++ks) {
    bf16x8 ah[2];
#pragma unroll
    for (int rf = 0; rf < 2; ++rf) {
      int row = rowbase + rf * 16 + lr;
      if (FUSEIN) {
        float xv = (row < N) ? X[row] : 0.f;
        int kbase = (ks * 4 + lg) * 8;
#pragma unroll
        for (int q = 0; q < 8; ++q) {
          float v = fmaxf(fmaf(xv, sWin[kbase + q], sbin[kbase + q]), 0.f);
          ah[rf][q] = (short)f2bf(v);
        }
      } else {
        ah[rf] = A8[row * 16 + ks * 4 + lg];
      }
    }
#pragma unroll
    for (int cf = 0; cf < 8; ++cf) {
      int n = (cf << 4) | lr;
      int us8 = ((n << 4) | ((ks * 4 + lg) ^ (n & 7))) * 8;
      bf16x8 wh = *(const bf16x8*)(sWhi + us8);
      bf16x8 wl = *(const bf16x8*)(sWlo + us8);
      acc[0][cf] = __builtin_amdgcn_mfma_f32_16x16x32_bf16(ah[0], wh, acc[0][cf], 0, 0, 0);
      acc[1][cf] = __builtin_amdgcn_mfma_f32_16x16x32_bf16(ah[1], wh, acc[1][cf], 0, 0, 0);
      acc[0][cf] = __builtin_amdgcn_mfma_f32_16x16x32_bf16(ah[0], wl, acc[0][cf], 0, 0, 0);
      acc[1][cf] = __builtin_amdgcn_mfma_f32_16x16x32_bf16(ah[1], wl, acc[1][cf], 0, 0, 0);
    }
  }
  // C/D layout: col = lane&15, row = (lane>>4)*4 + j   [m89-verified]
  int even = (lane & 1) == 0;
#pragma unroll
  for (int rf = 0; rf < 2; ++rf) {
#pragma unroll
    for (int cf = 0; cf < 8; ++cf) {
      int r0 = rowbase + rf * 16 + lg * 4;
      int cn = (cf << 4) | lr;
      int colb = cn & ~1;
      unsigned int u0 = f2bf(acc[rf][cf][0]);
      unsigned int u1 = f2bf(acc[rf][cf][1]);
      unsigned int u2 = f2bf(acc[rf][cf][2]);
      unsigned int u3 = f2bf(acc[rf][cf][3]);
      unsigned int p0 = (unsigned int)__shfl_xor((int)u0, 1);
      unsigned int p1 = (unsigned int)__shfl_xor((int)u1, 1);
      unsigned int p2 = (unsigned int)__shfl_xor((int)u2, 1);
      unsigned int p3 = (unsigned int)__shfl_xor((int)u3, 1);
      unsigned int pkA, pkB;
      int rA;
      if (even) { pkA = u0 | (p0 << 16); pkB = u1 | (p1 << 16); rA = r0; }
      else      { pkA = p2 | (u2 << 16); pkB = p3 | (u3 << 16); rA = r0 + 2; }
      *(unsigned int*)(Cs + (size_t)rA * 128 + colb) = pkA;
      *(unsigned int*)(Cs + (size_t)(rA + 1) * 128 + colb) = pkB;
    }
  }
}

// out = relu( dn*(sum_in ds*xw[s] + dn*xw[n]) + b ) -> single bf16 h
// both sides in one dispatch; 64 lanes/node, 4x edge unroll (accum order unchanged)
__global__ __launch_bounds__(256) void aggregate_kernel(const unsigned short* __restrict__ xw,
                                                        const float* __restrict__ dinv,
                                                        const int* __restrict__ rowstart,
                                                        const int* __restrict__ csr,
                                                        const float* __restrict__ bias,
                                                        unsigned short* __restrict__ hb) {
  int bid = blockIdx.x;
  int side = (bid >= AGGB) ? 1 : 0;
  bid -= side * AGGB;
  int idx = bid * 256 + threadIdx.x;
  int node = idx >> 6;
  int lane = idx & 63;
  if (node >= N) return;
  const unsigned int* xw2 = (const unsigned int*)xw + (size_t)side * NPAD * 64;
  const float* dv = dinv + (size_t)side * N;
  const int* rs = rowstart + (size_t)side * (N + 1);
  const int* cs = csr + (size_t)side * E;
  float dn = dv[node];
  unsigned int v = xw2[(size_t)node * 64 + lane];
  float a0 = dn * bf2f((unsigned short)v);
  float a1 = dn * bf2f((unsigned short)(v >> 16));
  int p0 = rs[node], p1 = rs[node + 1];
  int p = p0;
  for (; p + 4 <= p1; p += 4) {
    int s0 = cs[p], s1 = cs[p + 1], s2 = cs[p + 2], s3 = cs[p + 3];
    float d0 = dv[s0], d1 = dv[s1], d2 = dv[s2], d3 = dv[s3];
    unsigned int u0 = xw2[(size_t)s0 * 64 + lane];
    unsigned int u1 = xw2[(size_t)s1 * 64 + lane];
    unsigned int u2 = xw2[(size_t)s2 * 64 + lane];
    unsigned int u3 = xw2[(size_t)s3 * 64 + lane];
    a0 = fmaf(d0, bf2f((unsigned short)u0), a0);
    a1 = fmaf(d0, bf2f((unsigned short)(u0 >> 16)), a1);
    a0 = fmaf(d1, bf2f((unsigned short)u1), a0);
    a1 = fmaf(d1, bf2f((unsigned short)(u1 >> 16)), a1);
    a0 = fmaf(d2, bf2f((unsigned short)u2), a0);
    a1 = fmaf(d2, bf2f((unsigned short)(u2 >> 16)), a1);
    a0 = fmaf(d3, bf2f((unsigned short)u3), a0);
    a1 = fmaf(d3, bf2f((unsigned short)(u3 >> 16)), a1);
  }
  for (; p < p1; ++p) {
    int s = cs[p];
    float ds = dv[s];
    unsigned int u = xw2[(size_t)s * 64 + lane];
    a0 = fmaf(ds, bf2f((unsigned short)u), a0);
    a1 = fmaf(ds, bf2f((unsigned short)(u >> 16)), a1);
  }
  float2 b = ((const float2*)bias)[lane];
  float r0 = fmaxf(fmaf(dn, a0, b.x), 0.f);
  float r1 = fmaxf(fmaf(dn, a1, b.y), 0.f);
  unsigned int pk = (unsigned int)f2bf(r0) | ((unsigned int)f2bf(r1) << 16);
  ((unsigned int*)hb)[((size_t)side * NPAD + node) * 64 + lane] = pk;
}

// segment-mean pooling from single-bf16 h; both sides; 32 lanes per graph
__global__ void pool_kernel(const unsigned short* __restrict__ hb,
                            const int* __restrict__ gstart,
                            float* __restrict__ pooled) {
  int bid = blockIdx.x;
  int side = (bid >= (G * 32) / 256) ? 1 : 0;
  bid -= side * ((G * 32) / 256);
  int idx = bid * 256 + threadIdx.x;
  int grp = idx >> 5;
  int lane = idx & 31;
  if (grp >= G) return;
  const int* gs = gstart + side * (G + 1);
  const ushort4* h4 = (const ushort4*)(hb + (size_t)side * NPAD * H);
  int n0 = gs[grp], n1 = gs[grp + 1];
  float4 acc = {0.f, 0.f, 0.f, 0.f};
  for (int nn = n0; nn < n1; ++nn) {
    ushort4 hv = h4[(size_t)nn * 32 + lane];
    acc.x += bf2f(hv.x);
    acc.y += bf2f(hv.y);
    acc.z += bf2f(hv.z);
    acc.w += bf2f(hv.w);
  }
  float inv = 1.0f / fmaxf((float)(n1 - n0), 1.0f);
  acc.x *= inv; acc.y *= inv; acc.z *= inv; acc.w *= inv;
  ((float4*)(pooled + (size_t)side * G * H))[(size_t)grp * 32 + lane] = acc;
}

// ---------------- small f32 GEMM (pooled[2G] @ W_out, bias+relu) ----------------
template <bool EPI>
__global__ __launch_bounds__(256) void gemm128_kernel(const float* __restrict__ A,
                                                      const float* __restrict__ W,
                                                      const float* __restrict__ bias,
                                                      float* __restrict__ C, int rows) {
  __shared__ float sW[H * H];
  __shared__ float sA[32 * H];
  int t = threadIdx.x;
  for (int i = t; i < H * H / 4; i += 256)
    ((float4*)sW)[i] = ((const float4*)W)[i];
  int tr = t >> 5;
  int tc = t & 31;
  float4 bv = {0.f, 0.f, 0.f, 0.f};
  if (EPI) bv = ((const float4*)bias)[tc];
  int ntiles = (rows + 31) >> 5;
  for (int tile = blockIdx.x; tile < ntiles; tile += gridDim.x) {
    int row0 = tile << 5;
    __syncthreads();
    for (int i = t; i < 1024; i += 256) {
      int r = i >> 5, c = i & 31;
      int gr = row0 + r;
      float4 v = {0.f, 0.f, 0.f, 0.f};
      if (gr < rows) v = ((const float4*)A)[(size_t)gr * 32 + c];
      ((float4*)sA)[i] = v;
    }
    __syncthreads();
    float acc[4][4];
#pragma unroll
    for (int i = 0; i < 4; ++i)
#pragma unroll
      for (int j = 0; j < 4; ++j) acc[i][j] = 0.f;
    const float4* sA4 = (const float4*)sA;
    const float4* sW4 = (const float4*)sW;
#pragma unroll 4
    for (int k4 = 0; k4 < 32; ++k4) {
      float4 a0 = sA4[(tr * 4 + 0) * 32 + k4];
      float4 a1 = sA4[(tr * 4 + 1) * 32 + k4];
      float4 a2 = sA4[(tr * 4 + 2) * 32 + k4];
      float4 a3 = sA4[(tr * 4 + 3) * 32 + k4];
      float av[4][4] = {{a0.x, a0.y, a0.z, a0.w},
                        {a1.x, a1.y, a1.z, a1.w},
                        {a2.x, a2.y, a2.z, a2.w},
                        {a3.x, a3.y, a3.z, a3.w}};
#pragma unroll
      for (int kk = 0; kk < 4; ++kk) {
        float4 w = sW4[(k4 * 4 + kk) * 32 + tc];
#pragma unroll
        for (int i = 0; i < 4; ++i) {
          acc[i][0] = fmaf(av[i][kk], w.x, acc[i][0]);
          acc[i][1] = fmaf(av[i][kk], w.y, acc[i][1]);
          acc[i][2] = fmaf(av[i][kk], w.z, acc[i][2]);
          acc[i][3] = fmaf(av[i][kk], w.w, acc[i][3]);
        }
      }
    }
#pragma unroll
    for (int i = 0; i < 4; ++i) {
      int gr = row0 + tr * 4 + i;
      if (gr < rows) {
        float4 r;
        r.x = acc[i][0]; r.y = acc[i][1]; r.z = acc[i][2]; r.w = acc[i][3];
        if (EPI) {
          r.x = fmaxf(r.x + bv.x, 0.f);
          r.y = fmaxf(r.y + bv.y, 0.f);
          r.z = fmaxf(r.z + bv.z, 0.f);
          r.w = fmaxf(r.w + bv.w, 0.f);
        }
        ((float4*)C)[(size_t)gr * 32 + tc] = r;
      }
    }
  }
}

// per-graph MLP head: GPB graphs per block, 128 threads
__global__ __launch_bounds__(128) void classifier_kernel(const float* __restrict__ za,
                                                         const float* __restrict__ zb,
                                                         const float* __restrict__ Wm1,
                                                         const float* __restrict__ bm1,
                                                         const float* __restrict__ Wm2,
                                                         const float* __restrict__ bm2,
                                                         float* __restrict__ out, int g) {
  __shared__ float feats[GPB][4 * H];
  __shared__ float part[GPB][2];
  int j = threadIdx.x;
  int g0 = blockIdx.x * GPB;
#pragma unroll
  for (int q = 0; q < GPB; ++q) {
    float a = za[(size_t)(g0 + q) * H + j];
    float b = zb[(size_t)(g0 + q) * H + j];
    feats[q][j] = a;
    feats[q][H + j] = b;
    feats[q][2 * H + j] = fabsf(a - b);
    feats[q][3 * H + j] = a * b;
  }
  __syncthreads();
  float s[GPB];
  float b1 = bm1[j];
#pragma unroll
  for (int q = 0; q < GPB; ++q) s[q] = b1;
#pragma unroll 4
  for (int k = 0; k < 4 * H; ++k) {
    float w = Wm1[(size_t)k * H + j];
#pragma unroll
    for (int q = 0; q < GPB; ++q) s[q] = fmaf(feats[q][k], w, s[q]);
  }
  float w2 = Wm2[j];
  int lane = j & 63, wv = j >> 6;
#pragma unroll
  for (int q = 0; q < GPB; ++q) {
    float v = fmaxf(s[q], 0.f) * w2;
    for (int off = 32; off > 0; off >>= 1) v += __shfl_down(v, off);
    if (lane == 0) part[q][wv] = v;
  }
  __syncthreads();
  if (j < GPB) out[g0 + j] = part[j][0] + part[j][1] + bm2[0];
}

// ---------------- launch ----------------

extern "C" void kernel_launch(void* const* d_in, const int* in_sizes, int n_in,
                              void* d_out, int out_size, void* d_ws, size_t ws_size,
                              hipStream_t stream) {
  const float* xa = (const float*)d_in[0];
  const int* ei_a = (const int*)d_in[1];
  const int* bv_a = (const int*)d_in[2];
  const float* xb = (const float*)d_in[3];
  const int* ei_b = (const int*)d_in[4];
  const int* bv_b = (const int*)d_in[5];
  const float* W_in = (const float*)d_in[6];
  const float* b_in = (const float*)d_in[7];
  const float* W_c[3] = {(const float*)d_in[8], (const float*)d_in[10], (const float*)d_in[12]};
  const float* b_c[3] = {(const float*)d_in[9], (const float*)d_in[11], (const float*)d_in[13]};
  const float* W_out = (const float*)d_in[14];
  const float* b_out = (const float*)d_in[15];
  const float* W_m1 = (const float*)d_in[16];
  const float* b_m1 = (const float*)d_in[17];
  const float* W_m2 = (const float*)d_in[18];
  const float* b_m2 = (const float*)d_in[19];
  float* out = (float*)d_out;

  char* ws = (char*)d_ws;
  size_t off = 0;
  auto alloc = [&](size_t bytes) -> void* {
    void* p = ws + off;
    off += (bytes + 255) & ~(size_t)255;
    return p;
  };
  unsigned short* xwb = (unsigned short*)alloc((size_t)2 * NPAD * H * 2);  // 102.4 MB bf16
  unsigned short* hb = (unsigned short*)alloc((size_t)2 * NPAD * H * 2);   // 102.4 MB bf16
  unsigned int* binned = (unsigned int*)alloc((size_t)2 * NBK * BKCAP * 4);  // 8 MB
  int* binCnt = (int*)alloc((size_t)2 * NBK * 4);
  int* bucketBase = (int*)alloc((size_t)2 * NBK * 4);
  int* rowstart = (int*)alloc((size_t)2 * (N + 1) * 4);
  int* csr = (int*)alloc((size_t)2 * E * 4);
  float* dinv = (float*)alloc((size_t)2 * N * 4);
  int* gstart = (int*)alloc((size_t)2 * (G + 1) * 4);
  float* pooled = (float*)alloc((size_t)2 * G * H * 4);
  float* z = (float*)alloc((size_t)2 * G * H * 4);

  // graph build: bucketed two-pass CSR (both sides batched)
  hipMemsetAsync(binCnt, 0, (size_t)2 * NBK * 4, stream);
  bin_kernel<<<2 * NCH, 256, 0, stream>>>(ei_a, ei_b, binCnt, binned);
  bucketbase_kernel<<<1, 256, 0, stream>>>(binCnt, bucketBase);
  csrbuild_kernel<<<2 * NBK, 256, 0, stream>>>(binned, binCnt, bucketBase, rowstart, dinv, csr);
  segstart2_kernel<<<2 * 782, 256, 0, stream>>>(bv_a, bv_b, gstart);

  // conv stack, both sides per dispatch (shared Siamese weights)
  gemm_mfma_kernel<true><<<2 * NTILES, 256, 0, stream>>>(nullptr, xa, xb, W_in, b_in, W_c[0], xwb);
  aggregate_kernel<<<2 * AGGB, 256, 0, stream>>>(xwb, dinv, rowstart, csr, b_c[0], hb);
  for (int c = 1; c < 3; ++c) {
    gemm_mfma_kernel<false><<<2 * NTILES, 256, 0, stream>>>(hb, nullptr, nullptr, nullptr, nullptr, W_c[c], xwb);
    aggregate_kernel<<<2 * AGGB, 256, 0, stream>>>(xwb, dinv, rowstart, csr, b_c[c], hb);
  }
  pool_kernel<<<2 * (G * 32) / 256, 256, 0, stream>>>(hb, gstart, pooled);
  gemm128_kernel<true><<<512, 256, 0, stream>>>(pooled, W_out, b_out, z, 2 * G);
  classifier_kernel<<<G / GPB, 128, 0, stream>>>(z, z + (size_t)G * H, W_m1, b_m1, W_m2, b_m2, out, G);
}